// Round 5
// baseline (1750.655 us; speedup 1.0000x reference)
//
#include <hip/hip_runtime.h>

#define PI2F 6.283185307179586476f

// ---------------------------------------------------------------------------
// 16-point DFT, natural order in/out, fully unrolled (two radix-4 layers).
// X[r] = sum_j a[j] W_16^{jr}.
// ---------------------------------------------------------------------------
__device__ __forceinline__ void dft16(float* xr, float* xi)
{
    const float W16R[16] = {1.f, 1.f, 1.f, 1.f,
                            1.f, 0.92387953251f, 0.70710678119f, 0.38268343236f,
                            1.f, 0.70710678119f, 0.f, -0.70710678119f,
                            1.f, 0.38268343236f, -0.70710678119f, -0.92387953251f};
    const float W16I[16] = {0.f, 0.f, 0.f, 0.f,
                            0.f, -0.38268343236f, -0.70710678119f, -0.92387953251f,
                            0.f, -0.70710678119f, -1.f, -0.70710678119f,
                            0.f, -0.92387953251f, -0.70710678119f, 0.38268343236f};

    float br[16], bi[16];
#pragma unroll
    for (int jl = 0; jl < 4; ++jl) {
        float a0r = xr[jl],      a0i = xi[jl];
        float a1r = xr[jl + 4],  a1i = xi[jl + 4];
        float a2r = xr[jl + 8],  a2i = xi[jl + 8];
        float a3r = xr[jl + 12], a3i = xi[jl + 12];
        float s02r = a0r + a2r, s02i = a0i + a2i;
        float d02r = a0r - a2r, d02i = a0i - a2i;
        float s13r = a1r + a3r, s13i = a1i + a3i;
        float d13r = a1r - a3r, d13i = a1i - a3i;
        br[jl + 0]  = s02r + s13r;  bi[jl + 0]  = s02i + s13i;
        br[jl + 4]  = d02r + d13i;  bi[jl + 4]  = d02i - d13r;
        br[jl + 8]  = s02r - s13r;  bi[jl + 8]  = s02i - s13i;
        br[jl + 12] = d02r - d13i;  bi[jl + 12] = d02i + d13r;
    }
#pragma unroll
    for (int pos = 0; pos < 16; ++pos) {
        float wr = W16R[pos], wi = W16I[pos];
        float tr = br[pos] * wr - bi[pos] * wi;
        bi[pos]  = br[pos] * wi + bi[pos] * wr;
        br[pos]  = tr;
    }
#pragma unroll
    for (int rl = 0; rl < 4; ++rl) {
        float a0r = br[4 * rl + 0], a0i = bi[4 * rl + 0];
        float a1r = br[4 * rl + 1], a1i = bi[4 * rl + 1];
        float a2r = br[4 * rl + 2], a2i = bi[4 * rl + 2];
        float a3r = br[4 * rl + 3], a3i = bi[4 * rl + 3];
        float s02r = a0r + a2r, s02i = a0i + a2i;
        float d02r = a0r - a2r, d02i = a0i - a2i;
        float s13r = a1r + a3r, s13i = a1i + a3i;
        float d13r = a1r - a3r, d13i = a1i - a3i;
        xr[rl + 0]  = s02r + s13r;  xi[rl + 0]  = s02i + s13i;
        xr[rl + 4]  = d02r + d13i;  xi[rl + 4]  = d02i - d13r;
        xr[rl + 8]  = s02r - s13r;  xi[rl + 8]  = s02i - s13i;
        xr[rl + 12] = d02r - d13i;  xi[rl + 12] = d02i + d13r;
    }
}

// ---------------------------------------------------------------------------
// Pass 1: radix-4 Stockham, n = N, s = 1, real input. Writes interleaved
// float2 (two contiguous float4 stores per thread).
// ---------------------------------------------------------------------------
__global__ __launch_bounds__(256) void fft4_first_c(const float* __restrict__ x,
                                                    float2* __restrict__ yc,
                                                    int Nq, float n_inv)
{
    int p = blockIdx.x * 256 + threadIdx.x;
    if (p >= Nq) return;

    float a = x[p];
    float b = x[p + Nq];
    float c = x[p + 2 * Nq];
    float d = x[p + 3 * Nq];

    float apc = a + c, amc = a - c;
    float bpd = b + d, bmd = b - d;

    float ang = -PI2F * ((float)p * n_inv);
    float w1i, w1r;
    __sincosf(ang, &w1i, &w1r);
    float w2r = w1r * w1r - w1i * w1i, w2i = 2.f * w1r * w1i;
    float w3r = w2r * w1r - w2i * w1i, w3i = w2r * w1i + w2i * w1r;

    float t2 = apc - bpd;
    float4 lo = make_float4(apc + bpd,            0.f,
                            amc * w1r + bmd * w1i, amc * w1i - bmd * w1r);
    float4 hi = make_float4(t2 * w2r,              t2 * w2i,
                            amc * w3r - bmd * w3i, amc * w3i + bmd * w3r);

    *(float4*)(yc + 4 * p)     = lo;
    *(float4*)(yc + 4 * p + 2) = hi;
}

// ---------------------------------------------------------------------------
// Workgroup-cooperative radix-256 Stockham pass, interleaved float2 I/O.
// SPLIT=1: final pass, writes split re/im arrays (the [2,N] output layout).
//
// Sub-FFT for t = q + s*p:  a_j = x[t + j*(N/256)],
//   y_r = W_n^{p*r} * sum_j a_j W_256^{jr},  dst = q + s*(256p + r),  n = N/s.
// 256-pt DFT via 16x16 CT: thread (f, j1) DFTs over j2, applies combined
// twiddle W_n^{r1*(j1*(n/256)+p)} (recurrence from one sincos), transposes
// via a SINGLE 16.7KB LDS buffer (re then im, sequentially) so 8 blocks/CU
// fit; thread (f, r1) DFTs over j1 and applies W_{n/16}^{p*r2}.
// LDS pad 260: float4 writes (4-way conflict, ~1.6x), scalar reads 2-way free.
// ---------------------------------------------------------------------------
template<int SPLIT>
__global__ __launch_bounds__(256, 8) void fft256_pass(const float2* __restrict__ xc,
                                                      float2* __restrict__ yc,
                                                      float* __restrict__ yre,
                                                      float* __restrict__ yim,
                                                      int Nq,        // N/256
                                                      int sl,        // log2(s)
                                                      float n_inv,   // 1/n
                                                      float n16_inv) // 16/n
{
    __shared__ __align__(16) float lds[16 * 260 + 4];

    const int tid = threadIdx.x;
    const int f   = tid & 15;
    const int k   = tid >> 4;          // = j1 in phase A, = r1 in phase B
    const int t   = blockIdx.x * 16 + f;
    const int s   = 1 << sl;
    const int q   = t & (s - 1);
    const int p   = t >> sl;

    // ---- phase A: load + inner DFT over j2 ----
    float ar[16], ai[16];
    const int j1 = k;
#pragma unroll
    for (int j2 = 0; j2 < 16; ++j2) {
        float2 v = xc[t + (j1 + 16 * j2) * Nq];
        ar[j2] = v.x;
        ai[j2] = v.y;
    }

    dft16(ar, ai);   // ar[r1] = B[j1][r1]

    // combined twiddle W_n^{r1*m}, m = j1*(n/256) + p (exact integer < 2^24);
    // one sincos + complex-multiply recurrence.
    {
        const int   m  = j1 * (Nq >> sl) + p;
        float ang = -PI2F * ((float)m * n_inv);
        float w1i, w1r;
        __sincosf(ang, &w1i, &w1r);
        float cw = w1r, sw = w1i;
#pragma unroll
        for (int r1 = 1; r1 < 16; ++r1) {
            float tr = ar[r1] * cw - ai[r1] * sw;
            ai[r1]   = ar[r1] * sw + ai[r1] * cw;
            ar[r1]   = tr;
            float ncw = cw * w1r - sw * w1i;
            sw = cw * w1i + sw * w1r;
            cw = ncw;
        }
    }

    // ---- LDS transpose, single buffer, re then im ----
    const int wbase = f * 260 + j1 * 16;
    const int rbase = f * 260 + k;      // k = r1 in phase B

    float er[16], ei[16];

#pragma unroll
    for (int v = 0; v < 4; ++v)
        *(float4*)&lds[wbase + 4 * v] =
            make_float4(ar[4 * v], ar[4 * v + 1], ar[4 * v + 2], ar[4 * v + 3]);
    __syncthreads();
#pragma unroll
    for (int jj = 0; jj < 16; ++jj)
        er[jj] = lds[rbase + jj * 16];
    __syncthreads();

#pragma unroll
    for (int v = 0; v < 4; ++v)
        *(float4*)&lds[wbase + 4 * v] =
            make_float4(ai[4 * v], ai[4 * v + 1], ai[4 * v + 2], ai[4 * v + 3]);
    __syncthreads();
#pragma unroll
    for (int jj = 0; jj < 16; ++jj)
        ei[jj] = lds[rbase + jj * 16];

    // ---- phase B: outer DFT over j1 + second twiddle + store ----
    dft16(er, ei);

    const int dstbase = q + ((256 * p + k) << sl);
    float ang2 = -PI2F * ((float)p * n16_inv);
    float u1i, u1r;
    __sincosf(ang2, &u1i, &u1r);

    if (SPLIT) {
        yre[dstbase] = er[0];
        yim[dstbase] = ei[0];
        float cw = u1r, sw = u1i;
#pragma unroll
        for (int r2 = 1; r2 < 16; ++r2) {
            int dst = dstbase + ((16 * r2) << sl);
            yre[dst] = er[r2] * cw - ei[r2] * sw;
            yim[dst] = er[r2] * sw + ei[r2] * cw;
            float ncw = cw * u1r - sw * u1i;
            sw = cw * u1i + sw * u1r;
            cw = ncw;
        }
    } else {
        yc[dstbase] = make_float2(er[0], ei[0]);
        float cw = u1r, sw = u1i;
#pragma unroll
        for (int r2 = 1; r2 < 16; ++r2) {
            int dst = dstbase + ((16 * r2) << sl);
            yc[dst] = make_float2(er[r2] * cw - ei[r2] * sw,
                                  er[r2] * sw + ei[r2] * cw);
            float ncw = cw * u1r - sw * u1i;
            sw = cw * u1i + sw * u1r;
            cw = ncw;
        }
    }
}

// ---------------------------------------------------------------------------
// Fallback path kernels (non-2^26 sizes): split-layout radix-4 Stockham and
// in-place radix-2 (both verified in earlier rounds).
// ---------------------------------------------------------------------------
__global__ __launch_bounds__(256) void fft4_first(const float* __restrict__ x,
                                                  float* __restrict__ yre,
                                                  float* __restrict__ yim,
                                                  int Nq, float n_inv)
{
    int p = blockIdx.x * 256 + threadIdx.x;
    if (p >= Nq) return;

    float a = x[p];
    float b = x[p + Nq];
    float c = x[p + 2 * Nq];
    float d = x[p + 3 * Nq];

    float apc = a + c, amc = a - c;
    float bpd = b + d, bmd = b - d;

    float ang = -PI2F * ((float)p * n_inv);
    float w1i, w1r;
    __sincosf(ang, &w1i, &w1r);
    float w2r = w1r * w1r - w1i * w1i, w2i = 2.f * w1r * w1i;
    float w3r = w2r * w1r - w2i * w1i, w3i = w2r * w1i + w2i * w1r;

    float t2 = apc - bpd;
    float4 r4, i4;
    r4.x = apc + bpd;                 i4.x = 0.f;
    r4.y = amc * w1r + bmd * w1i;     i4.y = amc * w1i - bmd * w1r;
    r4.z = t2 * w2r;                  i4.z = t2 * w2i;
    r4.w = amc * w3r - bmd * w3i;     i4.w = amc * w3i + bmd * w3r;

    *(float4*)(yre + 4 * p) = r4;
    *(float4*)(yim + 4 * p) = i4;
}

__global__ __launch_bounds__(256) void fft4_pass(const float* __restrict__ xre,
                                                 const float* __restrict__ xim,
                                                 float* __restrict__ yre,
                                                 float* __restrict__ yim,
                                                 int Nq, int sl, float n_inv)
{
    int t = blockIdx.x * 256 + threadIdx.x;
    if (t >= Nq) return;

    const int s = 1 << sl;
    const int q = t & (s - 1);
    const int p = t >> sl;

    float ar = xre[t],          ai = xim[t];
    float br = xre[t + Nq],     bi = xim[t + Nq];
    float cr = xre[t + 2 * Nq], ci = xim[t + 2 * Nq];
    float dr = xre[t + 3 * Nq], di = xim[t + 3 * Nq];

    float apcr = ar + cr, apci = ai + ci;
    float amcr = ar - cr, amci = ai - ci;
    float bpdr = br + dr, bpdi = bi + di;
    float bmdr = br - dr, bmdi = bi - di;

    float ang = -PI2F * ((float)p * n_inv);
    float w1i, w1r;
    __sincosf(ang, &w1i, &w1r);
    float w2r = w1r * w1r - w1i * w1i, w2i = 2.f * w1r * w1i;
    float w3r = w2r * w1r - w2i * w1i, w3i = w2r * w1i + w2i * w1r;

    const int dst = q + (p << (sl + 2));

    yre[dst] = apcr + bpdr;
    yim[dst] = apci + bpdi;

    float t1r = amcr + bmdi, t1i = amci - bmdr;
    yre[dst + s] = t1r * w1r - t1i * w1i;
    yim[dst + s] = t1r * w1i + t1i * w1r;

    float t2r = apcr - bpdr, t2i = apci - bpdi;
    yre[dst + 2 * s] = t2r * w2r - t2i * w2i;
    yim[dst + 2 * s] = t2r * w2i + t2i * w2r;

    float t3r = amcr - bmdi, t3i = amci + bmdr;
    yre[dst + 3 * s] = t3r * w3r - t3i * w3i;
    yim[dst + 3 * s] = t3r * w3i + t3i * w3r;
}

__global__ __launch_bounds__(256) void bitrev_load(const float* __restrict__ x,
                                                   float* __restrict__ re,
                                                   float* __restrict__ im,
                                                   int N, int logN)
{
    int i = blockIdx.x * 256 + threadIdx.x;
    if (i >= N) return;
    unsigned r = __brev((unsigned)i) >> (32 - logN);
    re[i] = x[r];
    im[i] = 0.f;
}

__global__ __launch_bounds__(256) void r2_stage(float* __restrict__ re,
                                                float* __restrict__ im,
                                                int Nh, int sl, float m_inv)
{
    int t = blockIdx.x * 256 + threadIdx.x;
    if (t >= Nh) return;
    const int half = 1 << sl;
    const int j = t & (half - 1);
    const int pos = ((t >> sl) << (sl + 1)) + j;

    float ang = -PI2F * ((float)j * m_inv);
    float wi, wr;
    __sincosf(ang, &wi, &wr);

    float ur = re[pos],         ui = im[pos];
    float vr0 = re[pos + half], vi0 = im[pos + half];
    float vr = vr0 * wr - vi0 * wi;
    float vi = vr0 * wi + vi0 * wr;

    re[pos] = ur + vr;         im[pos] = ui + vi;
    re[pos + half] = ur - vr;  im[pos + half] = ui - vi;
}

// ---------------------------------------------------------------------------

extern "C" void kernel_launch(void* const* d_in, const int* in_sizes, int n_in,
                              void* d_out, int out_size, void* d_ws, size_t ws_size,
                              hipStream_t stream)
{
    const float* x = (const float*)d_in[0];
    const int N = in_sizes[0];
    int logN = 0;
    while ((1 << logN) < N) ++logN;

    float* outre = (float*)d_out;
    float* outim = outre + N;

    const bool ws_ok = (ws_size >= (size_t)2 * (size_t)N * sizeof(float));
    float* wre = (float*)d_ws;
    float* wim = wre + N;

    if (logN == 26 && ws_ok) {
        // 26 = 2 + 8 + 8 + 8: radix-4 (real input) then 3x radix-256.
        // Intermediates are interleaved float2; last pass emits split [2,N].
        float2* wc = (float2*)d_ws;
        float2* oc = (float2*)d_out;
        const int Nq4 = N >> 2;
        hipLaunchKernelGGL(fft4_first_c, dim3(Nq4 / 256), dim3(256), 0, stream,
                           x, wc, Nq4, 1.0f / (float)N);
        const int Nq = N >> 8;
        const int blocks = N >> 12;
        const float fN = (float)N;
        // pass 2: s = 4,     n = 2^24   (ws -> out)
        hipLaunchKernelGGL((fft256_pass<0>), dim3(blocks), dim3(256), 0, stream,
                           wc, oc, (float*)nullptr, (float*)nullptr,
                           Nq, 2, 4.0f / fN, 64.0f / fN);
        // pass 3: s = 1024,  n = 2^16   (out -> ws)
        hipLaunchKernelGGL((fft256_pass<0>), dim3(blocks), dim3(256), 0, stream,
                           oc, wc, (float*)nullptr, (float*)nullptr,
                           Nq, 10, 1024.0f / fN, 16384.0f / fN);
        // pass 4: s = 2^18,  n = 256    (ws -> out, split re/im)
        hipLaunchKernelGGL((fft256_pass<1>), dim3(blocks), dim3(256), 0, stream,
                           wc, (float2*)nullptr, outre, outim,
                           Nq, 18, 1.0f / 256.0f, 1.0f / 16.0f);
    } else if (((logN & 1) == 0) && ws_ok) {
        // Generic radix-4 Stockham (verified path).
        const int Nq = N >> 2;
        const int nb = (Nq + 255) / 256;
        hipLaunchKernelGGL(fft4_first, dim3(nb), dim3(256), 0, stream,
                           x, outre, outim, Nq, 1.0f / (float)N);
        float* sre = outre; float* sim = outim;
        float* dre = wre;   float* dim_ = wim;
        const int npass = logN >> 1;
        for (int i = 2; i <= npass; ++i) {
            const int sl = 2 * (i - 1);
            const float n_inv = 1.0f / (float)(N >> sl);
            hipLaunchKernelGGL(fft4_pass, dim3(nb), dim3(256), 0, stream,
                               sre, sim, dre, dim_, Nq, sl, n_inv);
            float* tt;
            tt = sre; sre = dre; dre = tt;
            tt = sim; sim = dim_; dim_ = tt;
        }
    } else {
        const int nbN = (N + 255) / 256;
        hipLaunchKernelGGL(bitrev_load, dim3(nbN), dim3(256), 0, stream,
                           x, outre, outim, N, logN);
        const int Nh = N >> 1;
        const int nbh = (Nh + 255) / 256;
        for (int s = 0; s < logN; ++s) {
            const float m_inv = 1.0f / (float)(2 << s);
            hipLaunchKernelGGL(r2_stage, dim3(nbh), dim3(256), 0, stream,
                               outre, outim, Nh, s, m_inv);
        }
    }
}

// Round 6
// 947.140 us; speedup vs baseline: 1.8484x; 1.8484x over previous
//
#include <hip/hip_runtime.h>

#define PI2F 6.283185307179586476f

// ---------------------------------------------------------------------------
// 16-point DFT, natural order in/out, fully unrolled (two radix-4 layers).
// X[r] = sum_j a[j] W_16^{jr}.
// ---------------------------------------------------------------------------
__device__ __forceinline__ void dft16(float* xr, float* xi)
{
    const float W16R[16] = {1.f, 1.f, 1.f, 1.f,
                            1.f, 0.92387953251f, 0.70710678119f, 0.38268343236f,
                            1.f, 0.70710678119f, 0.f, -0.70710678119f,
                            1.f, 0.38268343236f, -0.70710678119f, -0.92387953251f};
    const float W16I[16] = {0.f, 0.f, 0.f, 0.f,
                            0.f, -0.38268343236f, -0.70710678119f, -0.92387953251f,
                            0.f, -0.70710678119f, -1.f, -0.70710678119f,
                            0.f, -0.92387953251f, -0.70710678119f, 0.38268343236f};

    float br[16], bi[16];
#pragma unroll
    for (int jl = 0; jl < 4; ++jl) {
        float a0r = xr[jl],      a0i = xi[jl];
        float a1r = xr[jl + 4],  a1i = xi[jl + 4];
        float a2r = xr[jl + 8],  a2i = xi[jl + 8];
        float a3r = xr[jl + 12], a3i = xi[jl + 12];
        float s02r = a0r + a2r, s02i = a0i + a2i;
        float d02r = a0r - a2r, d02i = a0i - a2i;
        float s13r = a1r + a3r, s13i = a1i + a3i;
        float d13r = a1r - a3r, d13i = a1i - a3i;
        br[jl + 0]  = s02r + s13r;  bi[jl + 0]  = s02i + s13i;
        br[jl + 4]  = d02r + d13i;  bi[jl + 4]  = d02i - d13r;
        br[jl + 8]  = s02r - s13r;  bi[jl + 8]  = s02i - s13i;
        br[jl + 12] = d02r - d13i;  bi[jl + 12] = d02i + d13r;
    }
#pragma unroll
    for (int pos = 0; pos < 16; ++pos) {
        float wr = W16R[pos], wi = W16I[pos];
        float tr = br[pos] * wr - bi[pos] * wi;
        bi[pos]  = br[pos] * wi + bi[pos] * wr;
        br[pos]  = tr;
    }
#pragma unroll
    for (int rl = 0; rl < 4; ++rl) {
        float a0r = br[4 * rl + 0], a0i = bi[4 * rl + 0];
        float a1r = br[4 * rl + 1], a1i = bi[4 * rl + 1];
        float a2r = br[4 * rl + 2], a2i = bi[4 * rl + 2];
        float a3r = br[4 * rl + 3], a3i = bi[4 * rl + 3];
        float s02r = a0r + a2r, s02i = a0i + a2i;
        float d02r = a0r - a2r, d02i = a0i - a2i;
        float s13r = a1r + a3r, s13i = a1i + a3i;
        float d13r = a1r - a3r, d13i = a1i - a3i;
        xr[rl + 0]  = s02r + s13r;  xi[rl + 0]  = s02i + s13i;
        xr[rl + 4]  = d02r + d13i;  xi[rl + 4]  = d02i - d13r;
        xr[rl + 8]  = s02r - s13r;  xi[rl + 8]  = s02i - s13i;
        xr[rl + 12] = d02r - d13i;  xi[rl + 12] = d02i + d13r;
    }
}

// ---------------------------------------------------------------------------
// Pass 1: radix-4 Stockham, n = N, s = 1, real input. Writes interleaved
// float2 (two contiguous float4 stores per thread).
// ---------------------------------------------------------------------------
__global__ __launch_bounds__(256) void fft4_first_c(const float* __restrict__ x,
                                                    float2* __restrict__ yc,
                                                    int Nq, float n_inv)
{
    int p = blockIdx.x * 256 + threadIdx.x;
    if (p >= Nq) return;

    float a = x[p];
    float b = x[p + Nq];
    float c = x[p + 2 * Nq];
    float d = x[p + 3 * Nq];

    float apc = a + c, amc = a - c;
    float bpd = b + d, bmd = b - d;

    float ang = -PI2F * ((float)p * n_inv);
    float w1i, w1r;
    __sincosf(ang, &w1i, &w1r);
    float w2r = w1r * w1r - w1i * w1i, w2i = 2.f * w1r * w1i;
    float w3r = w2r * w1r - w2i * w1i, w3i = w2r * w1i + w2i * w1r;

    float t2 = apc - bpd;
    float4 lo = make_float4(apc + bpd,            0.f,
                            amc * w1r + bmd * w1i, amc * w1i - bmd * w1r);
    float4 hi = make_float4(t2 * w2r,              t2 * w2i,
                            amc * w3r - bmd * w3i, amc * w3i + bmd * w3r);

    *(float4*)(yc + 4 * p)     = lo;
    *(float4*)(yc + 4 * p + 2) = hi;
}

// ---------------------------------------------------------------------------
// Workgroup-cooperative radix-256 Stockham pass, interleaved float2 I/O.
// SPLIT=1: final pass, writes split re/im arrays (the [2,N] output layout).
//
// NOTE on launch bounds: plain (256). Round-5's (256,8) capped VGPR at 64 and
// the register arrays spilled to scratch (VGPR_Count 32, WRITE_SIZE 2.6x).
// With no min-waves clause the compiler picks ~64 VGPR (round-4 evidence),
// giving 8 waves/SIMD by VGPR and 9 blocks/CU by LDS (16.5KB) -> no spill,
// high residency.
// ---------------------------------------------------------------------------
template<int SPLIT>
__global__ __launch_bounds__(256) void fft256_pass(const float2* __restrict__ xc,
                                                   float2* __restrict__ yc,
                                                   float* __restrict__ yre,
                                                   float* __restrict__ yim,
                                                   int Nq,        // N/256
                                                   int sl,        // log2(s)
                                                   float n_inv,   // 1/n
                                                   float n16_inv) // 16/n
{
    __shared__ __align__(16) float lds[16 * 260 + 4];

    const int tid = threadIdx.x;
    const int f   = tid & 15;
    const int k   = tid >> 4;          // = j1 in phase A, = r1 in phase B
    const int t   = blockIdx.x * 16 + f;
    const int s   = 1 << sl;
    const int q   = t & (s - 1);
    const int p   = t >> sl;

    // ---- phase A: load + inner DFT over j2 ----
    float ar[16], ai[16];
    const int j1 = k;
#pragma unroll
    for (int j2 = 0; j2 < 16; ++j2) {
        float2 v = xc[t + (j1 + 16 * j2) * Nq];
        ar[j2] = v.x;
        ai[j2] = v.y;
    }

    dft16(ar, ai);   // ar[r1] = B[j1][r1]

    // combined twiddle W_n^{r1*m}, m = j1*(n/256) + p (exact integer < 2^24);
    // one sincos + complex-multiply recurrence.
    {
        const int   m  = j1 * (Nq >> sl) + p;
        float ang = -PI2F * ((float)m * n_inv);
        float w1i, w1r;
        __sincosf(ang, &w1i, &w1r);
        float cw = w1r, sw = w1i;
#pragma unroll
        for (int r1 = 1; r1 < 16; ++r1) {
            float tr = ar[r1] * cw - ai[r1] * sw;
            ai[r1]   = ar[r1] * sw + ai[r1] * cw;
            ar[r1]   = tr;
            float ncw = cw * w1r - sw * w1i;
            sw = cw * w1i + sw * w1r;
            cw = ncw;
        }
    }

    // ---- LDS transpose, single buffer, re then im ----
    const int wbase = f * 260 + j1 * 16;
    const int rbase = f * 260 + k;      // k = r1 in phase B

    float er[16], ei[16];

#pragma unroll
    for (int v = 0; v < 4; ++v)
        *(float4*)&lds[wbase + 4 * v] =
            make_float4(ar[4 * v], ar[4 * v + 1], ar[4 * v + 2], ar[4 * v + 3]);
    __syncthreads();
#pragma unroll
    for (int jj = 0; jj < 16; ++jj)
        er[jj] = lds[rbase + jj * 16];
    __syncthreads();

#pragma unroll
    for (int v = 0; v < 4; ++v)
        *(float4*)&lds[wbase + 4 * v] =
            make_float4(ai[4 * v], ai[4 * v + 1], ai[4 * v + 2], ai[4 * v + 3]);
    __syncthreads();
#pragma unroll
    for (int jj = 0; jj < 16; ++jj)
        ei[jj] = lds[rbase + jj * 16];

    // ---- phase B: outer DFT over j1 + second twiddle + store ----
    dft16(er, ei);

    const int dstbase = q + ((256 * p + k) << sl);
    float ang2 = -PI2F * ((float)p * n16_inv);
    float u1i, u1r;
    __sincosf(ang2, &u1i, &u1r);

    if (SPLIT) {
        yre[dstbase] = er[0];
        yim[dstbase] = ei[0];
        float cw = u1r, sw = u1i;
#pragma unroll
        for (int r2 = 1; r2 < 16; ++r2) {
            int dst = dstbase + ((16 * r2) << sl);
            yre[dst] = er[r2] * cw - ei[r2] * sw;
            yim[dst] = er[r2] * sw + ei[r2] * cw;
            float ncw = cw * u1r - sw * u1i;
            sw = cw * u1i + sw * u1r;
            cw = ncw;
        }
    } else {
        yc[dstbase] = make_float2(er[0], ei[0]);
        float cw = u1r, sw = u1i;
#pragma unroll
        for (int r2 = 1; r2 < 16; ++r2) {
            int dst = dstbase + ((16 * r2) << sl);
            yc[dst] = make_float2(er[r2] * cw - ei[r2] * sw,
                                  er[r2] * sw + ei[r2] * cw);
            float ncw = cw * u1r - sw * u1i;
            sw = cw * u1i + sw * u1r;
            cw = ncw;
        }
    }
}

// ---------------------------------------------------------------------------
// Fallback path kernels (non-2^26 sizes): split-layout radix-4 Stockham and
// in-place radix-2 (both verified in earlier rounds).
// ---------------------------------------------------------------------------
__global__ __launch_bounds__(256) void fft4_first(const float* __restrict__ x,
                                                  float* __restrict__ yre,
                                                  float* __restrict__ yim,
                                                  int Nq, float n_inv)
{
    int p = blockIdx.x * 256 + threadIdx.x;
    if (p >= Nq) return;

    float a = x[p];
    float b = x[p + Nq];
    float c = x[p + 2 * Nq];
    float d = x[p + 3 * Nq];

    float apc = a + c, amc = a - c;
    float bpd = b + d, bmd = b - d;

    float ang = -PI2F * ((float)p * n_inv);
    float w1i, w1r;
    __sincosf(ang, &w1i, &w1r);
    float w2r = w1r * w1r - w1i * w1i, w2i = 2.f * w1r * w1i;
    float w3r = w2r * w1r - w2i * w1i, w3i = w2r * w1i + w2i * w1r;

    float t2 = apc - bpd;
    float4 r4, i4;
    r4.x = apc + bpd;                 i4.x = 0.f;
    r4.y = amc * w1r + bmd * w1i;     i4.y = amc * w1i - bmd * w1r;
    r4.z = t2 * w2r;                  i4.z = t2 * w2i;
    r4.w = amc * w3r - bmd * w3i;     i4.w = amc * w3i + bmd * w3r;

    *(float4*)(yre + 4 * p) = r4;
    *(float4*)(yim + 4 * p) = i4;
}

__global__ __launch_bounds__(256) void fft4_pass(const float* __restrict__ xre,
                                                 const float* __restrict__ xim,
                                                 float* __restrict__ yre,
                                                 float* __restrict__ yim,
                                                 int Nq, int sl, float n_inv)
{
    int t = blockIdx.x * 256 + threadIdx.x;
    if (t >= Nq) return;

    const int s = 1 << sl;
    const int q = t & (s - 1);
    const int p = t >> sl;

    float ar = xre[t],          ai = xim[t];
    float br = xre[t + Nq],     bi = xim[t + Nq];
    float cr = xre[t + 2 * Nq], ci = xim[t + 2 * Nq];
    float dr = xre[t + 3 * Nq], di = xim[t + 3 * Nq];

    float apcr = ar + cr, apci = ai + ci;
    float amcr = ar - cr, amci = ai - ci;
    float bpdr = br + dr, bpdi = bi + di;
    float bmdr = br - dr, bmdi = bi - di;

    float ang = -PI2F * ((float)p * n_inv);
    float w1i, w1r;
    __sincosf(ang, &w1i, &w1r);
    float w2r = w1r * w1r - w1i * w1i, w2i = 2.f * w1r * w1i;
    float w3r = w2r * w1r - w2i * w1i, w3i = w2r * w1i + w2i * w1r;

    const int dst = q + (p << (sl + 2));

    yre[dst] = apcr + bpdr;
    yim[dst] = apci + bpdi;

    float t1r = amcr + bmdi, t1i = amci - bmdr;
    yre[dst + s] = t1r * w1r - t1i * w1i;
    yim[dst + s] = t1r * w1i + t1i * w1r;

    float t2r = apcr - bpdr, t2i = apci - bpdi;
    yre[dst + 2 * s] = t2r * w2r - t2i * w2i;
    yim[dst + 2 * s] = t2r * w2i + t2i * w2r;

    float t3r = amcr - bmdi, t3i = amci + bmdr;
    yre[dst + 3 * s] = t3r * w3r - t3i * w3i;
    yim[dst + 3 * s] = t3r * w3i + t3i * w3r;
}

__global__ __launch_bounds__(256) void bitrev_load(const float* __restrict__ x,
                                                   float* __restrict__ re,
                                                   float* __restrict__ im,
                                                   int N, int logN)
{
    int i = blockIdx.x * 256 + threadIdx.x;
    if (i >= N) return;
    unsigned r = __brev((unsigned)i) >> (32 - logN);
    re[i] = x[r];
    im[i] = 0.f;
}

__global__ __launch_bounds__(256) void r2_stage(float* __restrict__ re,
                                                float* __restrict__ im,
                                                int Nh, int sl, float m_inv)
{
    int t = blockIdx.x * 256 + threadIdx.x;
    if (t >= Nh) return;
    const int half = 1 << sl;
    const int j = t & (half - 1);
    const int pos = ((t >> sl) << (sl + 1)) + j;

    float ang = -PI2F * ((float)j * m_inv);
    float wi, wr;
    __sincosf(ang, &wi, &wr);

    float ur = re[pos],         ui = im[pos];
    float vr0 = re[pos + half], vi0 = im[pos + half];
    float vr = vr0 * wr - vi0 * wi;
    float vi = vr0 * wi + vi0 * wr;

    re[pos] = ur + vr;         im[pos] = ui + vi;
    re[pos + half] = ur - vr;  im[pos + half] = ui - vi;
}

// ---------------------------------------------------------------------------

extern "C" void kernel_launch(void* const* d_in, const int* in_sizes, int n_in,
                              void* d_out, int out_size, void* d_ws, size_t ws_size,
                              hipStream_t stream)
{
    const float* x = (const float*)d_in[0];
    const int N = in_sizes[0];
    int logN = 0;
    while ((1 << logN) < N) ++logN;

    float* outre = (float*)d_out;
    float* outim = outre + N;

    const bool ws_ok = (ws_size >= (size_t)2 * (size_t)N * sizeof(float));
    float* wre = (float*)d_ws;
    float* wim = wre + N;

    if (logN == 26 && ws_ok) {
        // 26 = 2 + 8 + 8 + 8: radix-4 (real input) then 3x radix-256.
        // Intermediates are interleaved float2; last pass emits split [2,N].
        float2* wc = (float2*)d_ws;
        float2* oc = (float2*)d_out;
        const int Nq4 = N >> 2;
        hipLaunchKernelGGL(fft4_first_c, dim3(Nq4 / 256), dim3(256), 0, stream,
                           x, wc, Nq4, 1.0f / (float)N);
        const int Nq = N >> 8;
        const int blocks = N >> 12;
        const float fN = (float)N;
        // pass 2: s = 4,     n = 2^24   (ws -> out)
        hipLaunchKernelGGL((fft256_pass<0>), dim3(blocks), dim3(256), 0, stream,
                           wc, oc, (float*)nullptr, (float*)nullptr,
                           Nq, 2, 4.0f / fN, 64.0f / fN);
        // pass 3: s = 1024,  n = 2^16   (out -> ws)
        hipLaunchKernelGGL((fft256_pass<0>), dim3(blocks), dim3(256), 0, stream,
                           oc, wc, (float*)nullptr, (float*)nullptr,
                           Nq, 10, 1024.0f / fN, 16384.0f / fN);
        // pass 4: s = 2^18,  n = 256    (ws -> out, split re/im)
        hipLaunchKernelGGL((fft256_pass<1>), dim3(blocks), dim3(256), 0, stream,
                           wc, (float2*)nullptr, outre, outim,
                           Nq, 18, 1.0f / 256.0f, 1.0f / 16.0f);
    } else if (((logN & 1) == 0) && ws_ok) {
        // Generic radix-4 Stockham (verified path).
        const int Nq = N >> 2;
        const int nb = (Nq + 255) / 256;
        hipLaunchKernelGGL(fft4_first, dim3(nb), dim3(256), 0, stream,
                           x, outre, outim, Nq, 1.0f / (float)N);
        float* sre = outre; float* sim = outim;
        float* dre = wre;   float* dim_ = wim;
        const int npass = logN >> 1;
        for (int i = 2; i <= npass; ++i) {
            const int sl = 2 * (i - 1);
            const float n_inv = 1.0f / (float)(N >> sl);
            hipLaunchKernelGGL(fft4_pass, dim3(nb), dim3(256), 0, stream,
                               sre, sim, dre, dim_, Nq, sl, n_inv);
            float* tt;
            tt = sre; sre = dre; dre = tt;
            tt = sim; sim = dim_; dim_ = tt;
        }
    } else {
        const int nbN = (N + 255) / 256;
        hipLaunchKernelGGL(bitrev_load, dim3(nbN), dim3(256), 0, stream,
                           x, outre, outim, N, logN);
        const int Nh = N >> 1;
        const int nbh = (Nh + 255) / 256;
        for (int s = 0; s < logN; ++s) {
            const float m_inv = 1.0f / (float)(2 << s);
            hipLaunchKernelGGL(r2_stage, dim3(nbh), dim3(256), 0, stream,
                               outre, outim, Nh, s, m_inv);
        }
    }
}

// Round 7
// 533.876 us; speedup vs baseline: 3.2791x; 1.7741x over previous
//
#include <hip/hip_runtime.h>

#define PI2F 6.283185307179586476f

// ---------------------------------------------------------------------------
// 16-point DFT, natural order in/out, fully unrolled (two radix-4 layers).
// X[r] = sum_j a[j] W_16^{jr}.
// ---------------------------------------------------------------------------
__device__ __forceinline__ void dft16(float* xr, float* xi)
{
    const float W16R[16] = {1.f, 1.f, 1.f, 1.f,
                            1.f, 0.92387953251f, 0.70710678119f, 0.38268343236f,
                            1.f, 0.70710678119f, 0.f, -0.70710678119f,
                            1.f, 0.38268343236f, -0.70710678119f, -0.92387953251f};
    const float W16I[16] = {0.f, 0.f, 0.f, 0.f,
                            0.f, -0.38268343236f, -0.70710678119f, -0.92387953251f,
                            0.f, -0.70710678119f, -1.f, -0.70710678119f,
                            0.f, -0.92387953251f, -0.70710678119f, 0.38268343236f};

    float br[16], bi[16];
#pragma unroll
    for (int jl = 0; jl < 4; ++jl) {
        float a0r = xr[jl],      a0i = xi[jl];
        float a1r = xr[jl + 4],  a1i = xi[jl + 4];
        float a2r = xr[jl + 8],  a2i = xi[jl + 8];
        float a3r = xr[jl + 12], a3i = xi[jl + 12];
        float s02r = a0r + a2r, s02i = a0i + a2i;
        float d02r = a0r - a2r, d02i = a0i - a2i;
        float s13r = a1r + a3r, s13i = a1i + a3i;
        float d13r = a1r - a3r, d13i = a1i - a3i;
        br[jl + 0]  = s02r + s13r;  bi[jl + 0]  = s02i + s13i;
        br[jl + 4]  = d02r + d13i;  bi[jl + 4]  = d02i - d13r;
        br[jl + 8]  = s02r - s13r;  bi[jl + 8]  = s02i - s13i;
        br[jl + 12] = d02r - d13i;  bi[jl + 12] = d02i + d13r;
    }
#pragma unroll
    for (int pos = 0; pos < 16; ++pos) {
        float wr = W16R[pos], wi = W16I[pos];
        float tr = br[pos] * wr - bi[pos] * wi;
        bi[pos]  = br[pos] * wi + bi[pos] * wr;
        br[pos]  = tr;
    }
#pragma unroll
    for (int rl = 0; rl < 4; ++rl) {
        float a0r = br[4 * rl + 0], a0i = bi[4 * rl + 0];
        float a1r = br[4 * rl + 1], a1i = bi[4 * rl + 1];
        float a2r = br[4 * rl + 2], a2i = bi[4 * rl + 2];
        float a3r = br[4 * rl + 3], a3i = bi[4 * rl + 3];
        float s02r = a0r + a2r, s02i = a0i + a2i;
        float d02r = a0r - a2r, d02i = a0i - a2i;
        float s13r = a1r + a3r, s13i = a1i + a3i;
        float d13r = a1r - a3r, d13i = a1i - a3i;
        xr[rl + 0]  = s02r + s13r;  xi[rl + 0]  = s02i + s13i;
        xr[rl + 4]  = d02r + d13i;  xi[rl + 4]  = d02i - d13r;
        xr[rl + 8]  = s02r - s13r;  xi[rl + 8]  = s02i - s13i;
        xr[rl + 12] = d02r - d13i;  xi[rl + 12] = d02i + d13r;
    }
}

// ---------------------------------------------------------------------------
// Workgroup-cooperative radix-256 Stockham pass, interleaved float2 I/O.
// SPLIT=1 variant writes split re/im (used only by the fallback path).
// Generic in (Nq = M/256, sl = log2(s)); verified on HW for sl=2,10,18.
// Plain __launch_bounds__(256): (256,8) caused scratch spills (round 5).
// ---------------------------------------------------------------------------
template<int SPLIT>
__global__ __launch_bounds__(256) void fft256_pass(const float2* __restrict__ xc,
                                                   float2* __restrict__ yc,
                                                   float* __restrict__ yre,
                                                   float* __restrict__ yim,
                                                   int Nq,        // M/256
                                                   int sl,        // log2(s)
                                                   float n_inv,   // 1/n
                                                   float n16_inv) // 16/n
{
    __shared__ __align__(16) float lds[16 * 260 + 4];

    const int tid = threadIdx.x;
    const int f   = tid & 15;
    const int k   = tid >> 4;          // = j1 in phase A, = r1 in phase B
    const int t   = blockIdx.x * 16 + f;
    const int s   = 1 << sl;
    const int q   = t & (s - 1);
    const int p   = t >> sl;

    // ---- phase A: load + inner DFT over j2 ----
    float ar[16], ai[16];
    const int j1 = k;
#pragma unroll
    for (int j2 = 0; j2 < 16; ++j2) {
        float2 v = xc[t + (j1 + 16 * j2) * Nq];
        ar[j2] = v.x;
        ai[j2] = v.y;
    }

    dft16(ar, ai);   // ar[r1] = B[j1][r1]

    // combined twiddle W_n^{r1*m}, m = j1*(n/256) + p (exact integer < 2^24);
    // one sincos + complex-multiply recurrence.
    {
        const int   m  = j1 * (Nq >> sl) + p;
        float ang = -PI2F * ((float)m * n_inv);
        float w1i, w1r;
        __sincosf(ang, &w1i, &w1r);
        float cw = w1r, sw = w1i;
#pragma unroll
        for (int r1 = 1; r1 < 16; ++r1) {
            float tr = ar[r1] * cw - ai[r1] * sw;
            ai[r1]   = ar[r1] * sw + ai[r1] * cw;
            ar[r1]   = tr;
            float ncw = cw * w1r - sw * w1i;
            sw = cw * w1i + sw * w1r;
            cw = ncw;
        }
    }

    // ---- LDS transpose, single 16.5KB buffer, re then im ----
    const int wbase = f * 260 + j1 * 16;
    const int rbase = f * 260 + k;      // k = r1 in phase B

    float er[16], ei[16];

#pragma unroll
    for (int v = 0; v < 4; ++v)
        *(float4*)&lds[wbase + 4 * v] =
            make_float4(ar[4 * v], ar[4 * v + 1], ar[4 * v + 2], ar[4 * v + 3]);
    __syncthreads();
#pragma unroll
    for (int jj = 0; jj < 16; ++jj)
        er[jj] = lds[rbase + jj * 16];
    __syncthreads();

#pragma unroll
    for (int v = 0; v < 4; ++v)
        *(float4*)&lds[wbase + 4 * v] =
            make_float4(ai[4 * v], ai[4 * v + 1], ai[4 * v + 2], ai[4 * v + 3]);
    __syncthreads();
#pragma unroll
    for (int jj = 0; jj < 16; ++jj)
        ei[jj] = lds[rbase + jj * 16];

    // ---- phase B: outer DFT over j1 + second twiddle + store ----
    dft16(er, ei);

    const int dstbase = q + ((256 * p + k) << sl);
    float ang2 = -PI2F * ((float)p * n16_inv);
    float u1i, u1r;
    __sincosf(ang2, &u1i, &u1r);

    if (SPLIT) {
        yre[dstbase] = er[0];
        yim[dstbase] = ei[0];
        float cw = u1r, sw = u1i;
#pragma unroll
        for (int r2 = 1; r2 < 16; ++r2) {
            int dst = dstbase + ((16 * r2) << sl);
            yre[dst] = er[r2] * cw - ei[r2] * sw;
            yim[dst] = er[r2] * sw + ei[r2] * cw;
            float ncw = cw * u1r - sw * u1i;
            sw = cw * u1i + sw * u1r;
            cw = ncw;
        }
    } else {
        yc[dstbase] = make_float2(er[0], ei[0]);
        float cw = u1r, sw = u1i;
#pragma unroll
        for (int r2 = 1; r2 < 16; ++r2) {
            int dst = dstbase + ((16 * r2) << sl);
            yc[dst] = make_float2(er[r2] * cw - ei[r2] * sw,
                                  er[r2] * sw + ei[r2] * cw);
            float ncw = cw * u1r - sw * u1i;
            sw = cw * u1i + sw * u1r;
            cw = ncw;
        }
    }
}

// ---------------------------------------------------------------------------
// Final pass of the real-input FFT: fused (last radix-2 Stockham stage) +
// (real-FFT untangle), Zp (M=2^25 complex, pre-radix-2) -> X (N=2^26, split).
//
// Radix-2 stage (s = K = M/2, p == 0, no twiddle):
//   Z[q]   = Zp[q] + Zp[q+K]
//   Z[q+K] = Zp[q] - Zp[q+K],  q in [0,K)
// Untangle (z[n] = x[2n] + i x[2n+1], Z = DFT_M(z)):
//   E[k] = (Z[k] + conj Z[M-k])/2,  O[k] = -i(Z[k] - conj Z[M-k])/2
//   X[k] = E + W_N^k O;  X[k+M] = E - W_N^k O;  X[N-j] = conj X[j]
// Thread k in [1, K/2] loads Zp[k], Zp[k+K], Zp[K-k], Zp[M-k] (each Zp
// element read exactly once chip-wide) and writes 8 spectrum points:
//   pair kappa=k   with W  = W_N^k
//   pair kappa=K-k with W' = W_N^{K-k} = -i conj(W)  (free)
// ---------------------------------------------------------------------------
__global__ __launch_bounds__(256) void rfft_final(const float2* __restrict__ Zp,
                                                  float* __restrict__ xre,
                                                  float* __restrict__ xim,
                                                  int K,          // M/2 = N/4
                                                  float w_scale)  // -2*pi/N
{
    const int k = blockIdx.x * 256 + threadIdx.x;
    const int half = K >> 1;
    if (k > half) return;
    const int M = K << 1;

    if (k == 0) {
        float2 A = Zp[0], B = Zp[K];
        float z0r = A.x + B.x, z0i = A.y + B.y;   // Z[0]
        float zkr = A.x - B.x, zki = A.y - B.y;   // Z[K]
        xre[0]     = z0r + z0i;  xim[0]     = 0.f;          // X[0]
        xre[M]     = z0r - z0i;  xim[M]     = 0.f;          // X[M] (Nyquist)
        xre[K]     = zkr;        xim[K]     = -zki;         // X[K]   = conj Z[K]
        xre[M + K] = zkr;        xim[M + K] = zki;          // X[M+K] = Z[K]
        return;
    }

    float2 A = Zp[k], B = Zp[k + K], C = Zp[K - k], D = Zp[M - k];

    float Z1r = A.x + B.x, Z1i = A.y + B.y;   // Z[k]
    float Zmr = C.x - D.x, Zmi = C.y - D.y;   // Z[M-k]   (= Z[(K-k)+K])
    float Y1r = C.x + D.x, Y1i = C.y + D.y;   // Z[K-k]
    float Ymr = A.x - B.x, Ymi = A.y - B.y;   // Z[K+k]   (= Z[M-(K-k)])

    float ang = w_scale * (float)k;           // -2*pi*k/N, |ang| <= pi/4
    float Wi, Wr;
    __sincosf(ang, &Wi, &Wr);

    // pair kappa = k
    {
        float Er = 0.5f * (Z1r + Zmr), Ei = 0.5f * (Z1i - Zmi);
        float Or = 0.5f * (Z1i + Zmi), Oi = 0.5f * (Zmr - Z1r);
        float WOr = Wr * Or - Wi * Oi, WOi = Wr * Oi + Wi * Or;
        float xr1 = Er + WOr, xi1 = Ei + WOi;   // X[k]
        float xr2 = Er - WOr, xi2 = Ei - WOi;   // X[k+M]
        xre[k]         = xr1;  xim[k]         = xi1;
        xre[k + M]     = xr2;  xim[k + M]     = xi2;
        xre[M - k]     = xr2;  xim[M - k]     = -xi2;   // conj X[k+M]
        xre[2 * M - k] = xr1;  xim[2 * M - k] = -xi1;   // X[N-k] = conj X[k]
    }
    // pair kappa = K - k,  W' = -i * conj(W) = (-Wi, -Wr)
    {
        float Wpr = -Wi, Wpi = -Wr;
        float Er = 0.5f * (Y1r + Ymr), Ei = 0.5f * (Y1i - Ymi);
        float Or = 0.5f * (Y1i + Ymi), Oi = 0.5f * (Ymr - Y1r);
        float WOr = Wpr * Or - Wpi * Oi, WOi = Wpr * Oi + Wpi * Or;
        float xr1 = Er + WOr, xi1 = Ei + WOi;   // X[K-k]
        float xr2 = Er - WOr, xi2 = Ei - WOi;   // X[K-k+M]
        xre[K - k]         = xr1;  xim[K - k]         = xi1;
        xre[K - k + M]     = xr2;  xim[K - k + M]     = xi2;
        xre[K + k]         = xr2;  xim[K + k]         = -xi2;  // M-(K-k)
        xre[M + K + k]     = xr1;  xim[M + K + k]     = -xi1;  // 2M-(K-k)
    }
}

// ---------------------------------------------------------------------------
// Fallback path kernels (non-2^26 sizes) — verified in earlier rounds.
// ---------------------------------------------------------------------------
__global__ __launch_bounds__(256) void fft4_first_c(const float* __restrict__ x,
                                                    float2* __restrict__ yc,
                                                    int Nq, float n_inv)
{
    int p = blockIdx.x * 256 + threadIdx.x;
    if (p >= Nq) return;

    float a = x[p];
    float b = x[p + Nq];
    float c = x[p + 2 * Nq];
    float d = x[p + 3 * Nq];

    float apc = a + c, amc = a - c;
    float bpd = b + d, bmd = b - d;

    float ang = -PI2F * ((float)p * n_inv);
    float w1i, w1r;
    __sincosf(ang, &w1i, &w1r);
    float w2r = w1r * w1r - w1i * w1i, w2i = 2.f * w1r * w1i;
    float w3r = w2r * w1r - w2i * w1i, w3i = w2r * w1i + w2i * w1r;

    float t2 = apc - bpd;
    float4 lo = make_float4(apc + bpd,            0.f,
                            amc * w1r + bmd * w1i, amc * w1i - bmd * w1r);
    float4 hi = make_float4(t2 * w2r,              t2 * w2i,
                            amc * w3r - bmd * w3i, amc * w3i + bmd * w3r);

    *(float4*)(yc + 4 * p)     = lo;
    *(float4*)(yc + 4 * p + 2) = hi;
}

__global__ __launch_bounds__(256) void fft4_first(const float* __restrict__ x,
                                                  float* __restrict__ yre,
                                                  float* __restrict__ yim,
                                                  int Nq, float n_inv)
{
    int p = blockIdx.x * 256 + threadIdx.x;
    if (p >= Nq) return;

    float a = x[p];
    float b = x[p + Nq];
    float c = x[p + 2 * Nq];
    float d = x[p + 3 * Nq];

    float apc = a + c, amc = a - c;
    float bpd = b + d, bmd = b - d;

    float ang = -PI2F * ((float)p * n_inv);
    float w1i, w1r;
    __sincosf(ang, &w1i, &w1r);
    float w2r = w1r * w1r - w1i * w1i, w2i = 2.f * w1r * w1i;
    float w3r = w2r * w1r - w2i * w1i, w3i = w2r * w1i + w2i * w1r;

    float t2 = apc - bpd;
    float4 r4, i4;
    r4.x = apc + bpd;                 i4.x = 0.f;
    r4.y = amc * w1r + bmd * w1i;     i4.y = amc * w1i - bmd * w1r;
    r4.z = t2 * w2r;                  i4.z = t2 * w2i;
    r4.w = amc * w3r - bmd * w3i;     i4.w = amc * w3i + bmd * w3r;

    *(float4*)(yre + 4 * p) = r4;
    *(float4*)(yim + 4 * p) = i4;
}

__global__ __launch_bounds__(256) void fft4_pass(const float* __restrict__ xre,
                                                 const float* __restrict__ xim,
                                                 float* __restrict__ yre,
                                                 float* __restrict__ yim,
                                                 int Nq, int sl, float n_inv)
{
    int t = blockIdx.x * 256 + threadIdx.x;
    if (t >= Nq) return;

    const int s = 1 << sl;
    const int q = t & (s - 1);
    const int p = t >> sl;

    float ar = xre[t],          ai = xim[t];
    float br = xre[t + Nq],     bi = xim[t + Nq];
    float cr = xre[t + 2 * Nq], ci = xim[t + 2 * Nq];
    float dr = xre[t + 3 * Nq], di = xim[t + 3 * Nq];

    float apcr = ar + cr, apci = ai + ci;
    float amcr = ar - cr, amci = ai - ci;
    float bpdr = br + dr, bpdi = bi + di;
    float bmdr = br - dr, bmdi = bi - di;

    float ang = -PI2F * ((float)p * n_inv);
    float w1i, w1r;
    __sincosf(ang, &w1i, &w1r);
    float w2r = w1r * w1r - w1i * w1i, w2i = 2.f * w1r * w1i;
    float w3r = w2r * w1r - w2i * w1i, w3i = w2r * w1i + w2i * w1r;

    const int dst = q + (p << (sl + 2));

    yre[dst] = apcr + bpdr;
    yim[dst] = apci + bpdi;

    float t1r = amcr + bmdi, t1i = amci - bmdr;
    yre[dst + s] = t1r * w1r - t1i * w1i;
    yim[dst + s] = t1r * w1i + t1i * w1r;

    float t2r = apcr - bpdr, t2i = apci - bpdi;
    yre[dst + 2 * s] = t2r * w2r - t2i * w2i;
    yim[dst + 2 * s] = t2r * w2i + t2i * w2r;

    float t3r = amcr - bmdi, t3i = amci + bmdr;
    yre[dst + 3 * s] = t3r * w3r - t3i * w3i;
    yim[dst + 3 * s] = t3r * w3i + t3i * w3r;
}

__global__ __launch_bounds__(256) void bitrev_load(const float* __restrict__ x,
                                                   float* __restrict__ re,
                                                   float* __restrict__ im,
                                                   int N, int logN)
{
    int i = blockIdx.x * 256 + threadIdx.x;
    if (i >= N) return;
    unsigned r = __brev((unsigned)i) >> (32 - logN);
    re[i] = x[r];
    im[i] = 0.f;
}

__global__ __launch_bounds__(256) void r2_stage(float* __restrict__ re,
                                                float* __restrict__ im,
                                                int Nh, int sl, float m_inv)
{
    int t = blockIdx.x * 256 + threadIdx.x;
    if (t >= Nh) return;
    const int half = 1 << sl;
    const int j = t & (half - 1);
    const int pos = ((t >> sl) << (sl + 1)) + j;

    float ang = -PI2F * ((float)j * m_inv);
    float wi, wr;
    __sincosf(ang, &wi, &wr);

    float ur = re[pos],         ui = im[pos];
    float vr0 = re[pos + half], vi0 = im[pos + half];
    float vr = vr0 * wr - vi0 * wi;
    float vi = vr0 * wi + vi0 * wr;

    re[pos] = ur + vr;         im[pos] = ui + vi;
    re[pos + half] = ur - vr;  im[pos + half] = ui - vi;
}

// ---------------------------------------------------------------------------

extern "C" void kernel_launch(void* const* d_in, const int* in_sizes, int n_in,
                              void* d_out, int out_size, void* d_ws, size_t ws_size,
                              hipStream_t stream)
{
    const float* x = (const float*)d_in[0];
    const int N = in_sizes[0];
    int logN = 0;
    while ((1 << logN) < N) ++logN;

    float* outre = (float*)d_out;
    float* outim = outre + N;

    if (logN == 26 && ws_size >= (size_t)(N / 2) * sizeof(float2)) {
        // Real-input FFT: z = float2 view of x (M = N/2 complex points).
        // M = 2^25 = 256^3 * 2: three radix-256 Stockham passes (s=1,256,65536)
        // + fused (radix-2 + untangle) final pass.
        // Buffers: din -> ws -> dout_lo(scratch) -> ws -> dout(split re/im).
        const int M  = N >> 1;           // 2^25
        const int K  = M >> 1;           // 2^24
        const int Nq = M >> 8;           // 2^17
        const int blocks = M >> 12;      // 8192
        const float fM = (float)M;

        const float2* zc = (const float2*)x;
        float2* wc = (float2*)d_ws;
        float2* oc = (float2*)d_out;     // lower 256MB of d_out as scratch

        // pass 1: s = 1      (din -> ws)
        hipLaunchKernelGGL((fft256_pass<0>), dim3(blocks), dim3(256), 0, stream,
                           zc, wc, (float*)nullptr, (float*)nullptr,
                           Nq, 0, 1.0f / fM, 16.0f / fM);
        // pass 2: s = 256    (ws -> dout scratch)
        hipLaunchKernelGGL((fft256_pass<0>), dim3(blocks), dim3(256), 0, stream,
                           wc, oc, (float*)nullptr, (float*)nullptr,
                           Nq, 8, 256.0f / fM, 4096.0f / fM);
        // pass 3: s = 65536  (dout scratch -> ws)
        hipLaunchKernelGGL((fft256_pass<0>), dim3(blocks), dim3(256), 0, stream,
                           oc, wc, (float*)nullptr, (float*)nullptr,
                           Nq, 16, 65536.0f / fM, 1048576.0f / fM);
        // final: fused radix-2 + untangle (ws -> dout split re/im; writes all)
        const int nthreads = (K >> 1) + 1;
        hipLaunchKernelGGL(rfft_final, dim3((nthreads + 255) / 256), dim3(256),
                           0, stream,
                           wc, outre, outim, K, -PI2F / (float)N);
    } else if (((logN & 1) == 0) &&
               ws_size >= (size_t)2 * (size_t)N * sizeof(float)) {
        // Generic radix-4 Stockham (verified path).
        float* wre = (float*)d_ws;
        float* wim = wre + N;
        const int Nq = N >> 2;
        const int nb = (Nq + 255) / 256;
        hipLaunchKernelGGL(fft4_first, dim3(nb), dim3(256), 0, stream,
                           x, outre, outim, Nq, 1.0f / (float)N);
        float* sre = outre; float* sim = outim;
        float* dre = wre;   float* dim_ = wim;
        const int npass = logN >> 1;
        for (int i = 2; i <= npass; ++i) {
            const int sl = 2 * (i - 1);
            const float n_inv = 1.0f / (float)(N >> sl);
            hipLaunchKernelGGL(fft4_pass, dim3(nb), dim3(256), 0, stream,
                               sre, sim, dre, dim_, Nq, sl, n_inv);
            float* tt;
            tt = sre; sre = dre; dre = tt;
            tt = sim; sim = dim_; dim_ = tt;
        }
    } else {
        const int nbN = (N + 255) / 256;
        hipLaunchKernelGGL(bitrev_load, dim3(nbN), dim3(256), 0, stream,
                           x, outre, outim, N, logN);
        const int Nh = N >> 1;
        const int nbh = (Nh + 255) / 256;
        for (int s = 0; s < logN; ++s) {
            const float m_inv = 1.0f / (float)(2 << s);
            hipLaunchKernelGGL(r2_stage, dim3(nbh), dim3(256), 0, stream,
                               outre, outim, Nh, s, m_inv);
        }
    }
}

// Round 8
// 510.964 us; speedup vs baseline: 3.4262x; 1.0448x over previous
//
#include <hip/hip_runtime.h>

#define PI2F 6.283185307179586476f

// ---------------------------------------------------------------------------
// 16-point DFT, natural order in/out, fully unrolled (two radix-4 layers).
// X[r] = sum_j a[j] W_16^{jr}.
// ---------------------------------------------------------------------------
__device__ __forceinline__ void dft16(float* xr, float* xi)
{
    const float W16R[16] = {1.f, 1.f, 1.f, 1.f,
                            1.f, 0.92387953251f, 0.70710678119f, 0.38268343236f,
                            1.f, 0.70710678119f, 0.f, -0.70710678119f,
                            1.f, 0.38268343236f, -0.70710678119f, -0.92387953251f};
    const float W16I[16] = {0.f, 0.f, 0.f, 0.f,
                            0.f, -0.38268343236f, -0.70710678119f, -0.92387953251f,
                            0.f, -0.70710678119f, -1.f, -0.70710678119f,
                            0.f, -0.92387953251f, -0.70710678119f, 0.38268343236f};

    float br[16], bi[16];
#pragma unroll
    for (int jl = 0; jl < 4; ++jl) {
        float a0r = xr[jl],      a0i = xi[jl];
        float a1r = xr[jl + 4],  a1i = xi[jl + 4];
        float a2r = xr[jl + 8],  a2i = xi[jl + 8];
        float a3r = xr[jl + 12], a3i = xi[jl + 12];
        float s02r = a0r + a2r, s02i = a0i + a2i;
        float d02r = a0r - a2r, d02i = a0i - a2i;
        float s13r = a1r + a3r, s13i = a1i + a3i;
        float d13r = a1r - a3r, d13i = a1i - a3i;
        br[jl + 0]  = s02r + s13r;  bi[jl + 0]  = s02i + s13i;
        br[jl + 4]  = d02r + d13i;  bi[jl + 4]  = d02i - d13r;
        br[jl + 8]  = s02r - s13r;  bi[jl + 8]  = s02i - s13i;
        br[jl + 12] = d02r - d13i;  bi[jl + 12] = d02i + d13r;
    }
#pragma unroll
    for (int pos = 0; pos < 16; ++pos) {
        float wr = W16R[pos], wi = W16I[pos];
        float tr = br[pos] * wr - bi[pos] * wi;
        bi[pos]  = br[pos] * wi + bi[pos] * wr;
        br[pos]  = tr;
    }
#pragma unroll
    for (int rl = 0; rl < 4; ++rl) {
        float a0r = br[4 * rl + 0], a0i = bi[4 * rl + 0];
        float a1r = br[4 * rl + 1], a1i = bi[4 * rl + 1];
        float a2r = br[4 * rl + 2], a2i = bi[4 * rl + 2];
        float a3r = br[4 * rl + 3], a3i = bi[4 * rl + 3];
        float s02r = a0r + a2r, s02i = a0i + a2i;
        float d02r = a0r - a2r, d02i = a0i - a2i;
        float s13r = a1r + a3r, s13i = a1i + a3i;
        float d13r = a1r - a3r, d13i = a1i - a3i;
        xr[rl + 0]  = s02r + s13r;  xi[rl + 0]  = s02i + s13i;
        xr[rl + 4]  = d02r + d13i;  xi[rl + 4]  = d02i - d13r;
        xr[rl + 8]  = s02r - s13r;  xi[rl + 8]  = s02i - s13i;
        xr[rl + 12] = d02r - d13i;  xi[rl + 12] = d02i + d13r;
    }
}

// ---------------------------------------------------------------------------
// Pass 1 (s = 1): radix-256 Stockham with contiguous stores.
// Identical math to fft256_pass<0> at sl=0, but after phase B the finished
// sub-FFTs are staged through the same 16.7KB LDS (viewed as a padded float2
// image, two batches of 8 sub-FFTs) and flushed lane-linearly:
//   yc[256*t_i + tid]  ->  512B contiguous per wave-instruction
// vs the generic kernel's 16x32B scattered chunks at s=1.
// ---------------------------------------------------------------------------
__global__ __launch_bounds__(256) void fft256_first(const float2* __restrict__ xc,
                                                    float2* __restrict__ yc,
                                                    int Nq,         // M/256
                                                    float m_inv,    // 1/M
                                                    float m16_inv)  // 16/M
{
    __shared__ __align__(16) float lds[16 * 260 + 4];  // >= 8*258 float2

    const int tid = threadIdx.x;
    const int f   = tid & 15;
    const int k   = tid >> 4;          // = j1 in phase A, = r1 in phase B
    const int t   = blockIdx.x * 16 + f;   // s=1: q=0, p=t

    // ---- phase A: load + inner DFT over j2 ----
    float ar[16], ai[16];
#pragma unroll
    for (int j2 = 0; j2 < 16; ++j2) {
        float2 v = xc[t + (k + 16 * j2) * Nq];
        ar[j2] = v.x;
        ai[j2] = v.y;
    }

    dft16(ar, ai);   // ar[r1] = B[j1][r1]

    // combined twiddle W_M^{r1*m}, m = j1*Nq + t  (exact integer < 2^22)
    {
        const float mf = (float)(k * Nq + t);
        float ang = -PI2F * (mf * m_inv);
        float w1i, w1r;
        __sincosf(ang, &w1i, &w1r);
        float cw = w1r, sw = w1i;
#pragma unroll
        for (int r1 = 1; r1 < 16; ++r1) {
            float tr = ar[r1] * cw - ai[r1] * sw;
            ai[r1]   = ar[r1] * sw + ai[r1] * cw;
            ar[r1]   = tr;
            float ncw = cw * w1r - sw * w1i;
            sw = cw * w1i + sw * w1r;
            cw = ncw;
        }
    }

    // ---- LDS transpose, single buffer, re then im ----
    const int wbase = f * 260 + k * 16;
    const int rbase = f * 260 + k;

    float er[16], ei[16];

#pragma unroll
    for (int v = 0; v < 4; ++v)
        *(float4*)&lds[wbase + 4 * v] =
            make_float4(ar[4 * v], ar[4 * v + 1], ar[4 * v + 2], ar[4 * v + 3]);
    __syncthreads();
#pragma unroll
    for (int jj = 0; jj < 16; ++jj)
        er[jj] = lds[rbase + jj * 16];
    __syncthreads();

#pragma unroll
    for (int v = 0; v < 4; ++v)
        *(float4*)&lds[wbase + 4 * v] =
            make_float4(ai[4 * v], ai[4 * v + 1], ai[4 * v + 2], ai[4 * v + 3]);
    __syncthreads();
#pragma unroll
    for (int jj = 0; jj < 16; ++jj)
        ei[jj] = lds[rbase + jj * 16];

    // ---- phase B: outer DFT over j1, r2-twiddle applied in registers ----
    dft16(er, ei);

    {
        float ang2 = -PI2F * ((float)t * m16_inv);
        float u1i, u1r;
        __sincosf(ang2, &u1i, &u1r);
        float cw = u1r, sw = u1i;
#pragma unroll
        for (int r2 = 1; r2 < 16; ++r2) {
            float tr = er[r2] * cw - ei[r2] * sw;
            ei[r2]   = er[r2] * sw + ei[r2] * cw;
            er[r2]   = tr;
            float ncw = cw * u1r - sw * u1i;
            sw = cw * u1i + sw * u1r;
            cw = ncw;
        }
    }

    // ---- staged contiguous store: two batches of 8 sub-FFTs ----
    // img rows stride 258 float2: write banks (4*fr + 2*k) -> 2-way (free);
    // read is canonical stride-1 b64.
    float2* img = (float2*)lds;
    __syncthreads();                    // lds reuse: transpose reads done
#pragma unroll
    for (int b = 0; b < 2; ++b) {
        if ((f >> 3) == b) {
            const int fr = f & 7;
#pragma unroll
            for (int r2 = 0; r2 < 16; ++r2)
                img[fr * 258 + k + 16 * r2] = make_float2(er[r2], ei[r2]);
        }
        __syncthreads();
        const int base = (blockIdx.x * 16 + 8 * b) * 256;
#pragma unroll
        for (int i = 0; i < 8; ++i)
            yc[base + i * 256 + tid] = img[i * 258 + tid];
        if (b == 0) __syncthreads();    // before batch 1 overwrites img
    }
}

// ---------------------------------------------------------------------------
// Workgroup-cooperative radix-256 Stockham pass, interleaved float2 I/O.
// Used for s = 256 and s = 65536 (stores there are 4x128B chunks per
// instruction -- structural max for a 16-column tile). SPLIT=1 writes split
// re/im (fallback path only).
// Plain __launch_bounds__(256): (256,8) caused scratch spills (round 5).
// ---------------------------------------------------------------------------
template<int SPLIT>
__global__ __launch_bounds__(256) void fft256_pass(const float2* __restrict__ xc,
                                                   float2* __restrict__ yc,
                                                   float* __restrict__ yre,
                                                   float* __restrict__ yim,
                                                   int Nq,        // M/256
                                                   int sl,        // log2(s)
                                                   float n_inv,   // 1/n
                                                   float n16_inv) // 16/n
{
    __shared__ __align__(16) float lds[16 * 260 + 4];

    const int tid = threadIdx.x;
    const int f   = tid & 15;
    const int k   = tid >> 4;          // = j1 in phase A, = r1 in phase B
    const int t   = blockIdx.x * 16 + f;
    const int s   = 1 << sl;
    const int q   = t & (s - 1);
    const int p   = t >> sl;

    // ---- phase A: load + inner DFT over j2 ----
    float ar[16], ai[16];
    const int j1 = k;
#pragma unroll
    for (int j2 = 0; j2 < 16; ++j2) {
        float2 v = xc[t + (j1 + 16 * j2) * Nq];
        ar[j2] = v.x;
        ai[j2] = v.y;
    }

    dft16(ar, ai);   // ar[r1] = B[j1][r1]

    // combined twiddle W_n^{r1*m}, m = j1*(n/256) + p (exact integer < 2^24);
    // one sincos + complex-multiply recurrence.
    {
        const int   m  = j1 * (Nq >> sl) + p;
        float ang = -PI2F * ((float)m * n_inv);
        float w1i, w1r;
        __sincosf(ang, &w1i, &w1r);
        float cw = w1r, sw = w1i;
#pragma unroll
        for (int r1 = 1; r1 < 16; ++r1) {
            float tr = ar[r1] * cw - ai[r1] * sw;
            ai[r1]   = ar[r1] * sw + ai[r1] * cw;
            ar[r1]   = tr;
            float ncw = cw * w1r - sw * w1i;
            sw = cw * w1i + sw * w1r;
            cw = ncw;
        }
    }

    // ---- LDS transpose, single 16.5KB buffer, re then im ----
    const int wbase = f * 260 + j1 * 16;
    const int rbase = f * 260 + k;      // k = r1 in phase B

    float er[16], ei[16];

#pragma unroll
    for (int v = 0; v < 4; ++v)
        *(float4*)&lds[wbase + 4 * v] =
            make_float4(ar[4 * v], ar[4 * v + 1], ar[4 * v + 2], ar[4 * v + 3]);
    __syncthreads();
#pragma unroll
    for (int jj = 0; jj < 16; ++jj)
        er[jj] = lds[rbase + jj * 16];
    __syncthreads();

#pragma unroll
    for (int v = 0; v < 4; ++v)
        *(float4*)&lds[wbase + 4 * v] =
            make_float4(ai[4 * v], ai[4 * v + 1], ai[4 * v + 2], ai[4 * v + 3]);
    __syncthreads();
#pragma unroll
    for (int jj = 0; jj < 16; ++jj)
        ei[jj] = lds[rbase + jj * 16];

    // ---- phase B: outer DFT over j1 + second twiddle + store ----
    dft16(er, ei);

    const int dstbase = q + ((256 * p + k) << sl);
    float ang2 = -PI2F * ((float)p * n16_inv);
    float u1i, u1r;
    __sincosf(ang2, &u1i, &u1r);

    if (SPLIT) {
        yre[dstbase] = er[0];
        yim[dstbase] = ei[0];
        float cw = u1r, sw = u1i;
#pragma unroll
        for (int r2 = 1; r2 < 16; ++r2) {
            int dst = dstbase + ((16 * r2) << sl);
            yre[dst] = er[r2] * cw - ei[r2] * sw;
            yim[dst] = er[r2] * sw + ei[r2] * cw;
            float ncw = cw * u1r - sw * u1i;
            sw = cw * u1i + sw * u1r;
            cw = ncw;
        }
    } else {
        yc[dstbase] = make_float2(er[0], ei[0]);
        float cw = u1r, sw = u1i;
#pragma unroll
        for (int r2 = 1; r2 < 16; ++r2) {
            int dst = dstbase + ((16 * r2) << sl);
            yc[dst] = make_float2(er[r2] * cw - ei[r2] * sw,
                                  er[r2] * sw + ei[r2] * cw);
            float ncw = cw * u1r - sw * u1i;
            sw = cw * u1i + sw * u1r;
            cw = ncw;
        }
    }
}

// ---------------------------------------------------------------------------
// Final pass of the real-input FFT: fused (last radix-2 Stockham stage) +
// (real-FFT untangle), Zp (M=2^25 complex, pre-radix-2) -> X (N=2^26, split).
//
// Radix-2 stage (s = K = M/2, p == 0, no twiddle):
//   Z[q]   = Zp[q] + Zp[q+K]
//   Z[q+K] = Zp[q] - Zp[q+K],  q in [0,K)
// Untangle (z[n] = x[2n] + i x[2n+1], Z = DFT_M(z)):
//   E[k] = (Z[k] + conj Z[M-k])/2,  O[k] = -i(Z[k] - conj Z[M-k])/2
//   X[k] = E + W_N^k O;  X[k+M] = E - W_N^k O;  X[N-j] = conj X[j]
// ---------------------------------------------------------------------------
__global__ __launch_bounds__(256) void rfft_final(const float2* __restrict__ Zp,
                                                  float* __restrict__ xre,
                                                  float* __restrict__ xim,
                                                  int K,          // M/2 = N/4
                                                  float w_scale)  // -2*pi/N
{
    const int k = blockIdx.x * 256 + threadIdx.x;
    const int half = K >> 1;
    if (k > half) return;
    const int M = K << 1;

    if (k == 0) {
        float2 A = Zp[0], B = Zp[K];
        float z0r = A.x + B.x, z0i = A.y + B.y;   // Z[0]
        float zkr = A.x - B.x, zki = A.y - B.y;   // Z[K]
        xre[0]     = z0r + z0i;  xim[0]     = 0.f;          // X[0]
        xre[M]     = z0r - z0i;  xim[M]     = 0.f;          // X[M] (Nyquist)
        xre[K]     = zkr;        xim[K]     = -zki;         // X[K]   = conj Z[K]
        xre[M + K] = zkr;        xim[M + K] = zki;          // X[M+K] = Z[K]
        return;
    }

    float2 A = Zp[k], B = Zp[k + K], C = Zp[K - k], D = Zp[M - k];

    float Z1r = A.x + B.x, Z1i = A.y + B.y;   // Z[k]
    float Zmr = C.x - D.x, Zmi = C.y - D.y;   // Z[M-k]   (= Z[(K-k)+K])
    float Y1r = C.x + D.x, Y1i = C.y + D.y;   // Z[K-k]
    float Ymr = A.x - B.x, Ymi = A.y - B.y;   // Z[K+k]   (= Z[M-(K-k)])

    float ang = w_scale * (float)k;           // -2*pi*k/N, |ang| <= pi/4
    float Wi, Wr;
    __sincosf(ang, &Wi, &Wr);

    // pair kappa = k
    {
        float Er = 0.5f * (Z1r + Zmr), Ei = 0.5f * (Z1i - Zmi);
        float Or = 0.5f * (Z1i + Zmi), Oi = 0.5f * (Zmr - Z1r);
        float WOr = Wr * Or - Wi * Oi, WOi = Wr * Oi + Wi * Or;
        float xr1 = Er + WOr, xi1 = Ei + WOi;   // X[k]
        float xr2 = Er - WOr, xi2 = Ei - WOi;   // X[k+M]
        xre[k]         = xr1;  xim[k]         = xi1;
        xre[k + M]     = xr2;  xim[k + M]     = xi2;
        xre[M - k]     = xr2;  xim[M - k]     = -xi2;   // conj X[k+M]
        xre[2 * M - k] = xr1;  xim[2 * M - k] = -xi1;   // X[N-k] = conj X[k]
    }
    // pair kappa = K - k,  W' = -i * conj(W) = (-Wi, -Wr)
    {
        float Wpr = -Wi, Wpi = -Wr;
        float Er = 0.5f * (Y1r + Ymr), Ei = 0.5f * (Y1i - Ymi);
        float Or = 0.5f * (Y1i + Ymi), Oi = 0.5f * (Ymr - Y1r);
        float WOr = Wpr * Or - Wpi * Oi, WOi = Wpr * Oi + Wpi * Or;
        float xr1 = Er + WOr, xi1 = Ei + WOi;   // X[K-k]
        float xr2 = Er - WOr, xi2 = Ei - WOi;   // X[K-k+M]
        xre[K - k]         = xr1;  xim[K - k]         = xi1;
        xre[K - k + M]     = xr2;  xim[K - k + M]     = xi2;
        xre[K + k]         = xr2;  xim[K + k]         = -xi2;  // M-(K-k)
        xre[M + K + k]     = xr1;  xim[M + K + k]     = -xi1;  // 2M-(K-k)
    }
}

// ---------------------------------------------------------------------------
// Fallback path kernels (non-2^26 sizes) — verified in earlier rounds.
// ---------------------------------------------------------------------------
__global__ __launch_bounds__(256) void fft4_first(const float* __restrict__ x,
                                                  float* __restrict__ yre,
                                                  float* __restrict__ yim,
                                                  int Nq, float n_inv)
{
    int p = blockIdx.x * 256 + threadIdx.x;
    if (p >= Nq) return;

    float a = x[p];
    float b = x[p + Nq];
    float c = x[p + 2 * Nq];
    float d = x[p + 3 * Nq];

    float apc = a + c, amc = a - c;
    float bpd = b + d, bmd = b - d;

    float ang = -PI2F * ((float)p * n_inv);
    float w1i, w1r;
    __sincosf(ang, &w1i, &w1r);
    float w2r = w1r * w1r - w1i * w1i, w2i = 2.f * w1r * w1i;
    float w3r = w2r * w1r - w2i * w1i, w3i = w2r * w1i + w2i * w1r;

    float t2 = apc - bpd;
    float4 r4, i4;
    r4.x = apc + bpd;                 i4.x = 0.f;
    r4.y = amc * w1r + bmd * w1i;     i4.y = amc * w1i - bmd * w1r;
    r4.z = t2 * w2r;                  i4.z = t2 * w2i;
    r4.w = amc * w3r - bmd * w3i;     i4.w = amc * w3i + bmd * w3r;

    *(float4*)(yre + 4 * p) = r4;
    *(float4*)(yim + 4 * p) = i4;
}

__global__ __launch_bounds__(256) void fft4_pass(const float* __restrict__ xre,
                                                 const float* __restrict__ xim,
                                                 float* __restrict__ yre,
                                                 float* __restrict__ yim,
                                                 int Nq, int sl, float n_inv)
{
    int t = blockIdx.x * 256 + threadIdx.x;
    if (t >= Nq) return;

    const int s = 1 << sl;
    const int q = t & (s - 1);
    const int p = t >> sl;

    float ar = xre[t],          ai = xim[t];
    float br = xre[t + Nq],     bi = xim[t + Nq];
    float cr = xre[t + 2 * Nq], ci = xim[t + 2 * Nq];
    float dr = xre[t + 3 * Nq], di = xim[t + 3 * Nq];

    float apcr = ar + cr, apci = ai + ci;
    float amcr = ar - cr, amci = ai - ci;
    float bpdr = br + dr, bpdi = bi + di;
    float bmdr = br - dr, bmdi = bi - di;

    float ang = -PI2F * ((float)p * n_inv);
    float w1i, w1r;
    __sincosf(ang, &w1i, &w1r);
    float w2r = w1r * w1r - w1i * w1i, w2i = 2.f * w1r * w1i;
    float w3r = w2r * w1r - w2i * w1i, w3i = w2r * w1i + w2i * w1r;

    const int dst = q + (p << (sl + 2));

    yre[dst] = apcr + bpdr;
    yim[dst] = apci + bpdi;

    float t1r = amcr + bmdi, t1i = amci - bmdr;
    yre[dst + s] = t1r * w1r - t1i * w1i;
    yim[dst + s] = t1r * w1i + t1i * w1r;

    float t2r = apcr - bpdr, t2i = apci - bpdi;
    yre[dst + 2 * s] = t2r * w2r - t2i * w2i;
    yim[dst + 2 * s] = t2r * w2i + t2i * w2r;

    float t3r = amcr - bmdi, t3i = amci + bmdr;
    yre[dst + 3 * s] = t3r * w3r - t3i * w3i;
    yim[dst + 3 * s] = t3r * w3i + t3i * w3r;
}

__global__ __launch_bounds__(256) void bitrev_load(const float* __restrict__ x,
                                                   float* __restrict__ re,
                                                   float* __restrict__ im,
                                                   int N, int logN)
{
    int i = blockIdx.x * 256 + threadIdx.x;
    if (i >= N) return;
    unsigned r = __brev((unsigned)i) >> (32 - logN);
    re[i] = x[r];
    im[i] = 0.f;
}

__global__ __launch_bounds__(256) void r2_stage(float* __restrict__ re,
                                                float* __restrict__ im,
                                                int Nh, int sl, float m_inv)
{
    int t = blockIdx.x * 256 + threadIdx.x;
    if (t >= Nh) return;
    const int half = 1 << sl;
    const int j = t & (half - 1);
    const int pos = ((t >> sl) << (sl + 1)) + j;

    float ang = -PI2F * ((float)j * m_inv);
    float wi, wr;
    __sincosf(ang, &wi, &wr);

    float ur = re[pos],         ui = im[pos];
    float vr0 = re[pos + half], vi0 = im[pos + half];
    float vr = vr0 * wr - vi0 * wi;
    float vi = vr0 * wi + vi0 * wr;

    re[pos] = ur + vr;         im[pos] = ui + vi;
    re[pos + half] = ur - vr;  im[pos + half] = ui - vi;
}

// ---------------------------------------------------------------------------

extern "C" void kernel_launch(void* const* d_in, const int* in_sizes, int n_in,
                              void* d_out, int out_size, void* d_ws, size_t ws_size,
                              hipStream_t stream)
{
    const float* x = (const float*)d_in[0];
    const int N = in_sizes[0];
    int logN = 0;
    while ((1 << logN) < N) ++logN;

    float* outre = (float*)d_out;
    float* outim = outre + N;

    if (logN == 26 && ws_size >= (size_t)(N / 2) * sizeof(float2)) {
        // Real-input FFT: z = float2 view of x (M = N/2 complex points).
        // M = 2^25 = 256^3 * 2: three radix-256 Stockham passes (s=1,256,65536)
        // + fused (radix-2 + untangle) final pass.
        // Buffers: din -> ws -> dout_lo(scratch) -> ws -> dout(split re/im).
        const int M  = N >> 1;           // 2^25
        const int K  = M >> 1;           // 2^24
        const int Nq = M >> 8;           // 2^17
        const int blocks = M >> 12;      // 8192
        const float fM = (float)M;

        const float2* zc = (const float2*)x;
        float2* wc = (float2*)d_ws;
        float2* oc = (float2*)d_out;     // lower 256MB of d_out as scratch

        // pass 1: s = 1      (din -> ws), contiguous-store variant
        hipLaunchKernelGGL(fft256_first, dim3(blocks), dim3(256), 0, stream,
                           zc, wc, Nq, 1.0f / fM, 16.0f / fM);
        // pass 2: s = 256    (ws -> dout scratch)
        hipLaunchKernelGGL((fft256_pass<0>), dim3(blocks), dim3(256), 0, stream,
                           wc, oc, (float*)nullptr, (float*)nullptr,
                           Nq, 8, 256.0f / fM, 4096.0f / fM);
        // pass 3: s = 65536  (dout scratch -> ws)
        hipLaunchKernelGGL((fft256_pass<0>), dim3(blocks), dim3(256), 0, stream,
                           oc, wc, (float*)nullptr, (float*)nullptr,
                           Nq, 16, 65536.0f / fM, 1048576.0f / fM);
        // final: fused radix-2 + untangle (ws -> dout split re/im; writes all)
        const int nthreads = (K >> 1) + 1;
        hipLaunchKernelGGL(rfft_final, dim3((nthreads + 255) / 256), dim3(256),
                           0, stream,
                           wc, outre, outim, K, -PI2F / (float)N);
    } else if (((logN & 1) == 0) &&
               ws_size >= (size_t)2 * (size_t)N * sizeof(float)) {
        // Generic radix-4 Stockham (verified path).
        float* wre = (float*)d_ws;
        float* wim = wre + N;
        const int Nq = N >> 2;
        const int nb = (Nq + 255) / 256;
        hipLaunchKernelGGL(fft4_first, dim3(nb), dim3(256), 0, stream,
                           x, outre, outim, Nq, 1.0f / (float)N);
        float* sre = outre; float* sim = outim;
        float* dre = wre;   float* dim_ = wim;
        const int npass = logN >> 1;
        for (int i = 2; i <= npass; ++i) {
            const int sl = 2 * (i - 1);
            const float n_inv = 1.0f / (float)(N >> sl);
            hipLaunchKernelGGL(fft4_pass, dim3(nb), dim3(256), 0, stream,
                               sre, sim, dre, dim_, Nq, sl, n_inv);
            float* tt;
            tt = sre; sre = dre; dre = tt;
            tt = sim; sim = dim_; dim_ = tt;
        }
    } else {
        const int nbN = (N + 255) / 256;
        hipLaunchKernelGGL(bitrev_load, dim3(nbN), dim3(256), 0, stream,
                           x, outre, outim, N, logN);
        const int Nh = N >> 1;
        const int nbh = (Nh + 255) / 256;
        for (int s = 0; s < logN; ++s) {
            const float m_inv = 1.0f / (float)(2 << s);
            hipLaunchKernelGGL(r2_stage, dim3(nbh), dim3(256), 0, stream,
                               outre, outim, Nh, s, m_inv);
        }
    }
}

// Round 9
// 498.786 us; speedup vs baseline: 3.5098x; 1.0244x over previous
//
#include <hip/hip_runtime.h>

#define PI2F 6.283185307179586476f

// ---------------------------------------------------------------------------
// 16-point DFT, natural order in/out, fully unrolled (two radix-4 layers).
// X[r] = sum_j a[j] W_16^{jr}.
// ---------------------------------------------------------------------------
__device__ __forceinline__ void dft16(float* xr, float* xi)
{
    const float W16R[16] = {1.f, 1.f, 1.f, 1.f,
                            1.f, 0.92387953251f, 0.70710678119f, 0.38268343236f,
                            1.f, 0.70710678119f, 0.f, -0.70710678119f,
                            1.f, 0.38268343236f, -0.70710678119f, -0.92387953251f};
    const float W16I[16] = {0.f, 0.f, 0.f, 0.f,
                            0.f, -0.38268343236f, -0.70710678119f, -0.92387953251f,
                            0.f, -0.70710678119f, -1.f, -0.70710678119f,
                            0.f, -0.92387953251f, -0.70710678119f, 0.38268343236f};

    float br[16], bi[16];
#pragma unroll
    for (int jl = 0; jl < 4; ++jl) {
        float a0r = xr[jl],      a0i = xi[jl];
        float a1r = xr[jl + 4],  a1i = xi[jl + 4];
        float a2r = xr[jl + 8],  a2i = xi[jl + 8];
        float a3r = xr[jl + 12], a3i = xi[jl + 12];
        float s02r = a0r + a2r, s02i = a0i + a2i;
        float d02r = a0r - a2r, d02i = a0i - a2i;
        float s13r = a1r + a3r, s13i = a1i + a3i;
        float d13r = a1r - a3r, d13i = a1i - a3i;
        br[jl + 0]  = s02r + s13r;  bi[jl + 0]  = s02i + s13i;
        br[jl + 4]  = d02r + d13i;  bi[jl + 4]  = d02i - d13r;
        br[jl + 8]  = s02r - s13r;  bi[jl + 8]  = s02i - s13i;
        br[jl + 12] = d02r - d13i;  bi[jl + 12] = d02i + d13r;
    }
#pragma unroll
    for (int pos = 0; pos < 16; ++pos) {
        float wr = W16R[pos], wi = W16I[pos];
        float tr = br[pos] * wr - bi[pos] * wi;
        bi[pos]  = br[pos] * wi + bi[pos] * wr;
        br[pos]  = tr;
    }
#pragma unroll
    for (int rl = 0; rl < 4; ++rl) {
        float a0r = br[4 * rl + 0], a0i = bi[4 * rl + 0];
        float a1r = br[4 * rl + 1], a1i = bi[4 * rl + 1];
        float a2r = br[4 * rl + 2], a2i = bi[4 * rl + 2];
        float a3r = br[4 * rl + 3], a3i = bi[4 * rl + 3];
        float s02r = a0r + a2r, s02i = a0i + a2i;
        float d02r = a0r - a2r, d02i = a0i - a2i;
        float s13r = a1r + a3r, s13i = a1i + a3i;
        float d13r = a1r - a3r, d13i = a1i - a3i;
        xr[rl + 0]  = s02r + s13r;  xi[rl + 0]  = s02i + s13i;
        xr[rl + 4]  = d02r + d13i;  xi[rl + 4]  = d02i - d13r;
        xr[rl + 8]  = s02r - s13r;  xi[rl + 8]  = s02i - s13i;
        xr[rl + 12] = d02r - d13i;  xi[rl + 12] = d02i + d13r;
    }
}

// ---------------------------------------------------------------------------
// Pass 1 (s = 1): radix-256 Stockham with contiguous stores (proven r8).
// After phase B the finished sub-FFTs are staged through LDS (padded float2
// image, two batches of 8 sub-FFTs) and flushed lane-linearly: 512B/wave.
// ---------------------------------------------------------------------------
__global__ __launch_bounds__(256) void fft256_first(const float2* __restrict__ xc,
                                                    float2* __restrict__ yc,
                                                    int Nq,         // M/256
                                                    float m_inv,    // 1/M
                                                    float m16_inv)  // 16/M
{
    __shared__ __align__(16) float lds[16 * 260 + 4];  // >= 8*258 float2

    const int tid = threadIdx.x;
    const int f   = tid & 15;
    const int k   = tid >> 4;          // = j1 in phase A, = r1 in phase B
    const int t   = blockIdx.x * 16 + f;   // s=1: q=0, p=t

    // ---- phase A: load + inner DFT over j2 ----
    float ar[16], ai[16];
#pragma unroll
    for (int j2 = 0; j2 < 16; ++j2) {
        float2 v = xc[t + (k + 16 * j2) * Nq];
        ar[j2] = v.x;
        ai[j2] = v.y;
    }

    dft16(ar, ai);   // ar[r1] = B[j1][r1]

    // combined twiddle W_M^{r1*m}, m = j1*Nq + t  (exact integer < 2^22)
    {
        const float mf = (float)(k * Nq + t);
        float ang = -PI2F * (mf * m_inv);
        float w1i, w1r;
        __sincosf(ang, &w1i, &w1r);
        float cw = w1r, sw = w1i;
#pragma unroll
        for (int r1 = 1; r1 < 16; ++r1) {
            float tr = ar[r1] * cw - ai[r1] * sw;
            ai[r1]   = ar[r1] * sw + ai[r1] * cw;
            ar[r1]   = tr;
            float ncw = cw * w1r - sw * w1i;
            sw = cw * w1i + sw * w1r;
            cw = ncw;
        }
    }

    // ---- LDS transpose, single buffer, re then im ----
    const int wbase = f * 260 + k * 16;
    const int rbase = f * 260 + k;

    float er[16], ei[16];

#pragma unroll
    for (int v = 0; v < 4; ++v)
        *(float4*)&lds[wbase + 4 * v] =
            make_float4(ar[4 * v], ar[4 * v + 1], ar[4 * v + 2], ar[4 * v + 3]);
    __syncthreads();
#pragma unroll
    for (int jj = 0; jj < 16; ++jj)
        er[jj] = lds[rbase + jj * 16];
    __syncthreads();

#pragma unroll
    for (int v = 0; v < 4; ++v)
        *(float4*)&lds[wbase + 4 * v] =
            make_float4(ai[4 * v], ai[4 * v + 1], ai[4 * v + 2], ai[4 * v + 3]);
    __syncthreads();
#pragma unroll
    for (int jj = 0; jj < 16; ++jj)
        ei[jj] = lds[rbase + jj * 16];

    // ---- phase B: outer DFT over j1, r2-twiddle applied in registers ----
    dft16(er, ei);

    {
        float ang2 = -PI2F * ((float)t * m16_inv);
        float u1i, u1r;
        __sincosf(ang2, &u1i, &u1r);
        float cw = u1r, sw = u1i;
#pragma unroll
        for (int r2 = 1; r2 < 16; ++r2) {
            float tr = er[r2] * cw - ei[r2] * sw;
            ei[r2]   = er[r2] * sw + ei[r2] * cw;
            er[r2]   = tr;
            float ncw = cw * u1r - sw * u1i;
            sw = cw * u1i + sw * u1r;
            cw = ncw;
        }
    }

    // ---- staged contiguous store: two batches of 8 sub-FFTs ----
    float2* img = (float2*)lds;
    __syncthreads();                    // lds reuse: transpose reads done
#pragma unroll
    for (int b = 0; b < 2; ++b) {
        if ((f >> 3) == b) {
            const int fr = f & 7;
#pragma unroll
            for (int r2 = 0; r2 < 16; ++r2)
                img[fr * 258 + k + 16 * r2] = make_float2(er[r2], ei[r2]);
        }
        __syncthreads();
        const int base = (blockIdx.x * 16 + 8 * b) * 256;
#pragma unroll
        for (int i = 0; i < 8; ++i)
            yc[base + i * 256 + tid] = img[i * 258 + tid];
        if (b == 0) __syncthreads();    // before batch 1 overwrites img
    }
}

// ---------------------------------------------------------------------------
// Middle passes (s = 256, 65536): radix-256 Stockham, 512 threads =
// 32 f (consecutive t) x 16 k. Per wave-instruction: 2 x 256B segments on
// loads AND stores (vs 4 x 128B at 256 threads) -- the r8 diagnosis was that
// 128B-chunk I/O capped these passes at ~4 TB/s.
// LDS: stride-257 rows (257 = 1 mod 32): transpose writes hit banks
// (f+16k+r1) mod 32 -> exactly 2 lanes/bank (free, m136); reads
// (f+16jj+k) mod 32 -> 2 lanes/bank (free). 32.2KB -> 4 blocks/CU; at the
// natural 64 VGPR that's 32 waves/CU. Plain launch_bounds (r5 spill lesson).
// ---------------------------------------------------------------------------
__global__ __launch_bounds__(512) void fft256_mid(const float2* __restrict__ xc,
                                                  float2* __restrict__ yc,
                                                  int Nq,        // M/256
                                                  int sl,        // log2(s)
                                                  float n_inv,   // 1/n
                                                  float n16_inv) // 16/n
{
    __shared__ float lds[32 * 257 + 4];

    const int tid = threadIdx.x;
    const int f   = tid & 31;
    const int k   = tid >> 5;          // = j1 in phase A, = r1 in phase B
    const int t   = blockIdx.x * 32 + f;
    const int s   = 1 << sl;
    const int q   = t & (s - 1);
    const int p   = t >> sl;           // uniform per block (32 | s)

    // ---- phase A: load + inner DFT over j2 ----
    float ar[16], ai[16];
#pragma unroll
    for (int j2 = 0; j2 < 16; ++j2) {
        float2 v = xc[t + (k + 16 * j2) * Nq];
        ar[j2] = v.x;
        ai[j2] = v.y;
    }

    dft16(ar, ai);   // ar[r1] = B[j1][r1]

    // combined twiddle W_n^{r1*m}, m = j1*(n/256) + p (exact integer < 2^24)
    {
        const int   m  = k * (Nq >> sl) + p;
        float ang = -PI2F * ((float)m * n_inv);
        float w1i, w1r;
        __sincosf(ang, &w1i, &w1r);
        float cw = w1r, sw = w1i;
#pragma unroll
        for (int r1 = 1; r1 < 16; ++r1) {
            float tr = ar[r1] * cw - ai[r1] * sw;
            ai[r1]   = ar[r1] * sw + ai[r1] * cw;
            ar[r1]   = tr;
            float ncw = cw * w1r - sw * w1i;
            sw = cw * w1i + sw * w1r;
            cw = ncw;
        }
    }

    // ---- LDS transpose, single 32.2KB buffer, re then im ----
    const int wbase = f * 257 + k * 16;
    const int rbase = f * 257 + k;

    float er[16], ei[16];

#pragma unroll
    for (int r1 = 0; r1 < 16; ++r1)
        lds[wbase + r1] = ar[r1];
    __syncthreads();
#pragma unroll
    for (int jj = 0; jj < 16; ++jj)
        er[jj] = lds[rbase + jj * 16];
    __syncthreads();

#pragma unroll
    for (int r1 = 0; r1 < 16; ++r1)
        lds[wbase + r1] = ai[r1];
    __syncthreads();
#pragma unroll
    for (int jj = 0; jj < 16; ++jj)
        ei[jj] = lds[rbase + jj * 16];

    // ---- phase B: outer DFT over j1 + second twiddle + store ----
    dft16(er, ei);

    const int dstbase = q + ((256 * p + k) << sl);
    float ang2 = -PI2F * ((float)p * n16_inv);
    float u1i, u1r;
    __sincosf(ang2, &u1i, &u1r);

    yc[dstbase] = make_float2(er[0], ei[0]);
    float cw = u1r, sw = u1i;
#pragma unroll
    for (int r2 = 1; r2 < 16; ++r2) {
        int dst = dstbase + ((16 * r2) << sl);
        yc[dst] = make_float2(er[r2] * cw - ei[r2] * sw,
                              er[r2] * sw + ei[r2] * cw);
        float ncw = cw * u1r - sw * u1i;
        sw = cw * u1i + sw * u1r;
        cw = ncw;
    }
}

// ---------------------------------------------------------------------------
// Final pass of the real-input FFT: fused (last radix-2 Stockham stage) +
// (real-FFT untangle), Zp (M=2^25 complex, pre-radix-2) -> X (N=2^26, split).
// Verified r7.
// ---------------------------------------------------------------------------
__global__ __launch_bounds__(256) void rfft_final(const float2* __restrict__ Zp,
                                                  float* __restrict__ xre,
                                                  float* __restrict__ xim,
                                                  int K,          // M/2 = N/4
                                                  float w_scale)  // -2*pi/N
{
    const int k = blockIdx.x * 256 + threadIdx.x;
    const int half = K >> 1;
    if (k > half) return;
    const int M = K << 1;

    if (k == 0) {
        float2 A = Zp[0], B = Zp[K];
        float z0r = A.x + B.x, z0i = A.y + B.y;   // Z[0]
        float zkr = A.x - B.x, zki = A.y - B.y;   // Z[K]
        xre[0]     = z0r + z0i;  xim[0]     = 0.f;          // X[0]
        xre[M]     = z0r - z0i;  xim[M]     = 0.f;          // X[M] (Nyquist)
        xre[K]     = zkr;        xim[K]     = -zki;         // X[K]   = conj Z[K]
        xre[M + K] = zkr;        xim[M + K] = zki;          // X[M+K] = Z[K]
        return;
    }

    float2 A = Zp[k], B = Zp[k + K], C = Zp[K - k], D = Zp[M - k];

    float Z1r = A.x + B.x, Z1i = A.y + B.y;   // Z[k]
    float Zmr = C.x - D.x, Zmi = C.y - D.y;   // Z[M-k]
    float Y1r = C.x + D.x, Y1i = C.y + D.y;   // Z[K-k]
    float Ymr = A.x - B.x, Ymi = A.y - B.y;   // Z[K+k]

    float ang = w_scale * (float)k;           // -2*pi*k/N
    float Wi, Wr;
    __sincosf(ang, &Wi, &Wr);

    // pair kappa = k
    {
        float Er = 0.5f * (Z1r + Zmr), Ei = 0.5f * (Z1i - Zmi);
        float Or = 0.5f * (Z1i + Zmi), Oi = 0.5f * (Zmr - Z1r);
        float WOr = Wr * Or - Wi * Oi, WOi = Wr * Oi + Wi * Or;
        float xr1 = Er + WOr, xi1 = Ei + WOi;   // X[k]
        float xr2 = Er - WOr, xi2 = Ei - WOi;   // X[k+M]
        xre[k]         = xr1;  xim[k]         = xi1;
        xre[k + M]     = xr2;  xim[k + M]     = xi2;
        xre[M - k]     = xr2;  xim[M - k]     = -xi2;
        xre[2 * M - k] = xr1;  xim[2 * M - k] = -xi1;
    }
    // pair kappa = K - k,  W' = -i * conj(W) = (-Wi, -Wr)
    {
        float Wpr = -Wi, Wpi = -Wr;
        float Er = 0.5f * (Y1r + Ymr), Ei = 0.5f * (Y1i - Ymi);
        float Or = 0.5f * (Y1i + Ymi), Oi = 0.5f * (Ymr - Y1r);
        float WOr = Wpr * Or - Wpi * Oi, WOi = Wpr * Oi + Wpi * Or;
        float xr1 = Er + WOr, xi1 = Ei + WOi;   // X[K-k]
        float xr2 = Er - WOr, xi2 = Ei - WOi;   // X[K-k+M]
        xre[K - k]         = xr1;  xim[K - k]         = xi1;
        xre[K - k + M]     = xr2;  xim[K - k + M]     = xi2;
        xre[K + k]         = xr2;  xim[K + k]         = -xi2;
        xre[M + K + k]     = xr1;  xim[M + K + k]     = -xi1;
    }
}

// ---------------------------------------------------------------------------
// Fallback path kernels (non-2^26 sizes) — verified in earlier rounds.
// ---------------------------------------------------------------------------
__global__ __launch_bounds__(256) void fft4_first(const float* __restrict__ x,
                                                  float* __restrict__ yre,
                                                  float* __restrict__ yim,
                                                  int Nq, float n_inv)
{
    int p = blockIdx.x * 256 + threadIdx.x;
    if (p >= Nq) return;

    float a = x[p];
    float b = x[p + Nq];
    float c = x[p + 2 * Nq];
    float d = x[p + 3 * Nq];

    float apc = a + c, amc = a - c;
    float bpd = b + d, bmd = b - d;

    float ang = -PI2F * ((float)p * n_inv);
    float w1i, w1r;
    __sincosf(ang, &w1i, &w1r);
    float w2r = w1r * w1r - w1i * w1i, w2i = 2.f * w1r * w1i;
    float w3r = w2r * w1r - w2i * w1i, w3i = w2r * w1i + w2i * w1r;

    float t2 = apc - bpd;
    float4 r4, i4;
    r4.x = apc + bpd;                 i4.x = 0.f;
    r4.y = amc * w1r + bmd * w1i;     i4.y = amc * w1i - bmd * w1r;
    r4.z = t2 * w2r;                  i4.z = t2 * w2i;
    r4.w = amc * w3r - bmd * w3i;     i4.w = amc * w3i + bmd * w3r;

    *(float4*)(yre + 4 * p) = r4;
    *(float4*)(yim + 4 * p) = i4;
}

__global__ __launch_bounds__(256) void fft4_pass(const float* __restrict__ xre,
                                                 const float* __restrict__ xim,
                                                 float* __restrict__ yre,
                                                 float* __restrict__ yim,
                                                 int Nq, int sl, float n_inv)
{
    int t = blockIdx.x * 256 + threadIdx.x;
    if (t >= Nq) return;

    const int s = 1 << sl;
    const int q = t & (s - 1);
    const int p = t >> sl;

    float ar = xre[t],          ai = xim[t];
    float br = xre[t + Nq],     bi = xim[t + Nq];
    float cr = xre[t + 2 * Nq], ci = xim[t + 2 * Nq];
    float dr = xre[t + 3 * Nq], di = xim[t + 3 * Nq];

    float apcr = ar + cr, apci = ai + ci;
    float amcr = ar - cr, amci = ai - ci;
    float bpdr = br + dr, bpdi = bi + di;
    float bmdr = br - dr, bmdi = bi - di;

    float ang = -PI2F * ((float)p * n_inv);
    float w1i, w1r;
    __sincosf(ang, &w1i, &w1r);
    float w2r = w1r * w1r - w1i * w1i, w2i = 2.f * w1r * w1i;
    float w3r = w2r * w1r - w2i * w1i, w3i = w2r * w1i + w2i * w1r;

    const int dst = q + (p << (sl + 2));

    yre[dst] = apcr + bpdr;
    yim[dst] = apci + bpdi;

    float t1r = amcr + bmdi, t1i = amci - bmdr;
    yre[dst + s] = t1r * w1r - t1i * w1i;
    yim[dst + s] = t1r * w1i + t1i * w1r;

    float t2r = apcr - bpdr, t2i = apci - bpdi;
    yre[dst + 2 * s] = t2r * w2r - t2i * w2i;
    yim[dst + 2 * s] = t2r * w2i + t2i * w2r;

    float t3r = amcr - bmdi, t3i = amci + bmdr;
    yre[dst + 3 * s] = t3r * w3r - t3i * w3i;
    yim[dst + 3 * s] = t3r * w3i + t3i * w3r;
}

__global__ __launch_bounds__(256) void bitrev_load(const float* __restrict__ x,
                                                   float* __restrict__ re,
                                                   float* __restrict__ im,
                                                   int N, int logN)
{
    int i = blockIdx.x * 256 + threadIdx.x;
    if (i >= N) return;
    unsigned r = __brev((unsigned)i) >> (32 - logN);
    re[i] = x[r];
    im[i] = 0.f;
}

__global__ __launch_bounds__(256) void r2_stage(float* __restrict__ re,
                                                float* __restrict__ im,
                                                int Nh, int sl, float m_inv)
{
    int t = blockIdx.x * 256 + threadIdx.x;
    if (t >= Nh) return;
    const int half = 1 << sl;
    const int j = t & (half - 1);
    const int pos = ((t >> sl) << (sl + 1)) + j;

    float ang = -PI2F * ((float)j * m_inv);
    float wi, wr;
    __sincosf(ang, &wi, &wr);

    float ur = re[pos],         ui = im[pos];
    float vr0 = re[pos + half], vi0 = im[pos + half];
    float vr = vr0 * wr - vi0 * wi;
    float vi = vr0 * wi + vi0 * wr;

    re[pos] = ur + vr;         im[pos] = ui + vi;
    re[pos + half] = ur - vr;  im[pos + half] = ui - vi;
}

// ---------------------------------------------------------------------------

extern "C" void kernel_launch(void* const* d_in, const int* in_sizes, int n_in,
                              void* d_out, int out_size, void* d_ws, size_t ws_size,
                              hipStream_t stream)
{
    const float* x = (const float*)d_in[0];
    const int N = in_sizes[0];
    int logN = 0;
    while ((1 << logN) < N) ++logN;

    float* outre = (float*)d_out;
    float* outim = outre + N;

    if (logN == 26 && ws_size >= (size_t)(N / 2) * sizeof(float2)) {
        // Real-input FFT: z = float2 view of x (M = N/2 complex points).
        // M = 2^25: three radix-256 Stockham passes (s=1,256,65536) + fused
        // (radix-2 + untangle) final pass.
        // Buffers: din -> ws -> dout_lo(scratch) -> ws -> dout(split re/im).
        const int M  = N >> 1;           // 2^25
        const int K  = M >> 1;           // 2^24
        const int Nq = M >> 8;           // 2^17
        const float fM = (float)M;

        const float2* zc = (const float2*)x;
        float2* wc = (float2*)d_ws;
        float2* oc = (float2*)d_out;     // lower 256MB of d_out as scratch

        // pass 1: s = 1      (din -> ws), 256-thr staged-store variant
        hipLaunchKernelGGL(fft256_first, dim3(M >> 12), dim3(256), 0, stream,
                           zc, wc, Nq, 1.0f / fM, 16.0f / fM);
        // pass 2: s = 256    (ws -> dout scratch), 512-thr wide-tile variant
        hipLaunchKernelGGL(fft256_mid, dim3(M >> 13), dim3(512), 0, stream,
                           wc, oc, Nq, 8, 256.0f / fM, 4096.0f / fM);
        // pass 3: s = 65536  (dout scratch -> ws)
        hipLaunchKernelGGL(fft256_mid, dim3(M >> 13), dim3(512), 0, stream,
                           oc, wc, Nq, 16, 65536.0f / fM, 1048576.0f / fM);
        // final: fused radix-2 + untangle (ws -> dout split re/im; writes all)
        const int nthreads = (K >> 1) + 1;
        hipLaunchKernelGGL(rfft_final, dim3((nthreads + 255) / 256), dim3(256),
                           0, stream,
                           wc, outre, outim, K, -PI2F / (float)N);
    } else if (((logN & 1) == 0) &&
               ws_size >= (size_t)2 * (size_t)N * sizeof(float)) {
        // Generic radix-4 Stockham (verified path).
        float* wre = (float*)d_ws;
        float* wim = wre + N;
        const int Nq = N >> 2;
        const int nb = (Nq + 255) / 256;
        hipLaunchKernelGGL(fft4_first, dim3(nb), dim3(256), 0, stream,
                           x, outre, outim, Nq, 1.0f / (float)N);
        float* sre = outre; float* sim = outim;
        float* dre = wre;   float* dim_ = wim;
        const int npass = logN >> 1;
        for (int i = 2; i <= npass; ++i) {
            const int sl = 2 * (i - 1);
            const float n_inv = 1.0f / (float)(N >> sl);
            hipLaunchKernelGGL(fft4_pass, dim3(nb), dim3(256), 0, stream,
                               sre, sim, dre, dim_, Nq, sl, n_inv);
            float* tt;
            tt = sre; sre = dre; dre = tt;
            tt = sim; sim = dim_; dim_ = tt;
        }
    } else {
        const int nbN = (N + 255) / 256;
        hipLaunchKernelGGL(bitrev_load, dim3(nbN), dim3(256), 0, stream,
                           x, outre, outim, N, logN);
        const int Nh = N >> 1;
        const int nbh = (Nh + 255) / 256;
        for (int s = 0; s < logN; ++s) {
            const float m_inv = 1.0f / (float)(2 << s);
            hipLaunchKernelGGL(r2_stage, dim3(nbh), dim3(256), 0, stream,
                               outre, outim, Nh, s, m_inv);
        }
    }
}